// Round 1
// 538.025 us; speedup vs baseline: 1.0485x; 1.0485x over previous
//
#include <hip/hip_runtime.h>
#include <hip/hip_fp16.h>
#include <math.h>

#define NN 100000
#define NE 1200000
#define NES (NE + NN)   // edges incl. self-loops
#define FIN 256
#define NBLK 391        // (NN + 255) / 256

using half8   = __attribute__((ext_vector_type(8))) _Float16;
using floatx4 = __attribute__((ext_vector_type(4))) float;

__device__ __forceinline__ floatx4 mfma16(half8 a, half8 b, floatx4 c) {
    return __builtin_amdgcn_mfma_f32_16x16x32_f16(a, b, c, 0, 0, 0);
}

// ---------------- fused histogram + degree: ONE packed u64 atomic per edge ----
// packed[d]: bits[48:63] = count, bits[0:47] = sum(w) in 2^-32 fixed point.
__global__ __launch_bounds__(256) void k_histdeg(const int* __restrict__ dst,
                                                 const float* __restrict__ ew,
                                                 unsigned long long* __restrict__ packed) {
    int e = blockIdx.x * 256 + threadIdx.x;
    if (e >= NES) return;
    int d; float w;
    if (e < NE) { d = dst[e]; w = ew[e]; } else { d = e - NE; w = 1.f; }
    unsigned long long add = (1ULL << 48)
        + (unsigned long long)((double)w * 4294967296.0);
    atomicAdd(&packed[d], add);
}

// ---------------- CSR build: scan (+ unpack, dinv, cursor-zero), fill ---------
__global__ __launch_bounds__(256) void k_scanA(const unsigned long long* __restrict__ packed,
                                               int* __restrict__ row_ptr,
                                               int* __restrict__ bsum,
                                               float* __restrict__ dinv,
                                               int* __restrict__ cur) {
    __shared__ int tmp[256];
    int tid = threadIdx.x;
    int i = blockIdx.x * 256 + tid;
    int v = 0;
    if (i < NN) {
        unsigned long long p = packed[i];
        v = (int)(p >> 48);
        double deg = (double)(p & 0xFFFFFFFFFFFFULL) * (1.0 / 4294967296.0);
        dinv[i] = (deg > 0.0) ? rsqrtf((float)deg) : 0.f;
        cur[i] = 0;
    }
    tmp[tid] = v;
    __syncthreads();
    for (int off = 1; off < 256; off <<= 1) {
        int t = (tid >= off) ? tmp[tid - off] : 0;
        __syncthreads();
        tmp[tid] += t;
        __syncthreads();
    }
    if (i < NN) row_ptr[i] = tmp[tid] - v;
    if (tid == 255) bsum[blockIdx.x] = tmp[255];
}

__global__ __launch_bounds__(512) void k_scanB(int* __restrict__ bsum) {
    __shared__ int tmp[512];
    int tid = threadIdx.x;
    int v = (tid < NBLK) ? bsum[tid] : 0;
    tmp[tid] = v;
    __syncthreads();
    for (int off = 1; off < 512; off <<= 1) {
        int t = (tid >= off) ? tmp[tid - off] : 0;
        __syncthreads();
        tmp[tid] += t;
        __syncthreads();
    }
    if (tid < NBLK) bsum[tid] = tmp[tid] - v;
}

__global__ __launch_bounds__(256) void k_scanC(int* __restrict__ row_ptr,
                                               const int* __restrict__ bsum) {
    int i = blockIdx.x * 256 + threadIdx.x;
    if (i < NN) row_ptr[i] += bsum[i >> 8];
    if (i == 0) row_ptr[NN] = NES;
}

// edge record: {src, float_bits(w * dinv[src])} — one 8B scattered store
__global__ __launch_bounds__(256) void k_fill(const int* __restrict__ src,
                                              const int* __restrict__ dst,
                                              const float* __restrict__ ew,
                                              const int* __restrict__ row_ptr,
                                              int* __restrict__ cur,
                                              const float* __restrict__ dinv,
                                              int2* __restrict__ recs) {
    int e = blockIdx.x * 256 + threadIdx.x;
    if (e >= NES) return;
    int s, d; float w;
    if (e < NE) { s = src[e]; d = dst[e]; w = ew[e]; } else { s = d = e - NE; w = 1.f; }
    int pos = row_ptr[d] + atomicAdd(&cur[d], 1);
    int2 r; r.x = s; r.y = __float_as_int(w * dinv[s]);
    recs[pos] = r;
}

// ---------------- single W pre-swizzle kernel (all 5 matrices + folded att) ---
// attf[layer*256 + v*64 + c], v: 0=src_h0 1=src_h1 2=dst_h0 3=dst_h1
// attf_v[c] = sum_j gat_W[c, h*64+j] * att[h, j]   (fold att through gat_W)
__global__ __launch_bounds__(256) void k_wconvall(const float* __restrict__ W0,
                                                  const float* __restrict__ W1,
                                                  const float* __restrict__ Wg0,
                                                  const float* __restrict__ Ws0,
                                                  const float* __restrict__ Wg1,
                                                  const float* __restrict__ Ws1,
                                                  const float* __restrict__ Wc,
                                                  const float* __restrict__ As0,
                                                  const float* __restrict__ Ad0,
                                                  const float* __restrict__ As1,
                                                  const float* __restrict__ Ad1,
                                                  __half* __restrict__ Wf,
                                                  float* __restrict__ attf) {
    int o = blockIdx.x * 256 + threadIdx.x;
    if (o >= 59904) return;
    if (o >= 59392) {
        int idx = o - 59392;          // 0..511
        int layer = idx >> 8, rem = idx & 255;
        int v = rem >> 6, c = rem & 63, h = v & 1;
        const float* Wg = layer ? Wg1 : Wg0;
        const float* av = (v < 2) ? (layer ? As1 : As0) : (layer ? Ad1 : Ad0);
        float s = 0.f;
        for (int jj = 0; jj < 64; ++jj)
            s = fmaf(Wg[c * 128 + h * 64 + jj], av[h * 64 + jj], s);
        attf[idx] = s;
        return;
    }
    int lo, NT, N; const float* Wg; const float* Wsg = nullptr;
    if (o < 16384)      { lo = o;         NT = 4;  N = 64; Wg = W0; }
    else if (o < 28672) { lo = o - 16384; NT = 4;  N = 64; Wg = W1; }
    else if (o < 40960) { lo = o - 28672; NT = 12; N = 0;  Wg = Wg0; Wsg = Ws0; }
    else if (o < 53248) { lo = o - 40960; NT = 12; N = 0;  Wg = Wg1; Wsg = Ws1; }
    else                { lo = o - 53248; NT = 2;  N = 32; Wg = Wc; }
    int j = lo & 7, n = (lo >> 3) & 15, q = (lo >> 7) & 3, rest = lo >> 9;
    int t = rest % NT, kc = rest / NT;
    int k = kc * 32 + q * 8 + j, col = t * 16 + n;
    float v;
    if (Wsg) v = (col < 128) ? Wg[(size_t)k * 128 + col] : Wsg[(size_t)k * 64 + (col - 128)];
    else     v = Wg[(size_t)k * N + col];
    Wf[o] = __float2half(v);
}

// ---------------- shared epilogue for pre-linear: store xh + a_src/a_dst ------
__device__ __forceinline__ void pre_epi(floatx4* acc, const float* b, const float* attf,
                                        float* a_src, float* a_dst, __half* out,
                                        int rowb, int q, int n) {
    float vs0[4] = {0,0,0,0}, vs1[4] = {0,0,0,0};
    float vd0[4] = {0,0,0,0}, vd1[4] = {0,0,0,0};
    #pragma unroll
    for (int t = 0; t < 4; ++t) {
        float bb  = b[t * 16 + n];
        float ws0 = attf[t * 16 + n],       ws1 = attf[64 + t * 16 + n];
        float wd0 = attf[128 + t * 16 + n], wd1 = attf[192 + t * 16 + n];
        #pragma unroll
        for (int r = 0; r < 4; ++r) {
            float xv = acc[t][r] + bb;
            int row = rowb + q * 4 + r;
            if (row < NN) out[(size_t)row * 64 + t * 16 + n] = __float2half(xv);
            vs0[r] = fmaf(xv, ws0, vs0[r]);
            vs1[r] = fmaf(xv, ws1, vs1[r]);
            vd0[r] = fmaf(xv, wd0, vd0[r]);
            vd1[r] = fmaf(xv, wd1, vd1[r]);
        }
    }
    #pragma unroll
    for (int off = 1; off < 16; off <<= 1) {
        #pragma unroll
        for (int r = 0; r < 4; ++r) {
            vs0[r] += __shfl_xor(vs0[r], off);
            vs1[r] += __shfl_xor(vs1[r], off);
            vd0[r] += __shfl_xor(vd0[r], off);
            vd1[r] += __shfl_xor(vd1[r], off);
        }
    }
    if (n == 0) {
        #pragma unroll
        for (int r = 0; r < 4; ++r) {
            int row = rowb + q * 4 + r;
            if (row < NN) {
                a_src[row * 2]     = vs0[r];
                a_src[row * 2 + 1] = vs1[r];
                a_dst[row * 2]     = vd0[r];
                a_dst[row * 2 + 1] = vd1[r];
            }
        }
    }
}

// ---------------- pre-linear (fp32 A): xh = x @ W[K,64] + b -> fp16 + att dots
template<int KK>
__global__ __launch_bounds__(256) void k_pre32(const float* __restrict__ A,
                                               const __half* __restrict__ Wf,
                                               const float* __restrict__ b,
                                               const float* __restrict__ attf,
                                               float* __restrict__ a_src,
                                               float* __restrict__ a_dst,
                                               __half* __restrict__ out) {
    int lane = threadIdx.x & 63, wv = threadIdx.x >> 6;
    int q = lane >> 4, n = lane & 15;
    int rowb = blockIdx.x * 64 + wv * 16;
    int rowA = rowb + n; if (rowA > NN - 1) rowA = NN - 1;
    floatx4 acc[4] = {};
    const float* ap = A + (size_t)rowA * KK + q * 8;
    const __half* wp = Wf + q * 128 + n * 8;
    #pragma unroll
    for (int kc = 0; kc < KK / 32; ++kc) {
        float4 f0 = *(const float4*)(ap + kc * 32);
        float4 f1 = *(const float4*)(ap + kc * 32 + 4);
        half8 a;
        a[0] = (_Float16)f0.x; a[1] = (_Float16)f0.y;
        a[2] = (_Float16)f0.z; a[3] = (_Float16)f0.w;
        a[4] = (_Float16)f1.x; a[5] = (_Float16)f1.y;
        a[6] = (_Float16)f1.z; a[7] = (_Float16)f1.w;
        #pragma unroll
        for (int t = 0; t < 4; ++t) {
            half8 bf = *(const half8*)(wp + (size_t)(kc * 4 + t) * 512);
            acc[t] = mfma16(a, bf, acc[t]);
        }
    }
    pre_epi(acc, b, attf, a_src, a_dst, out, rowb, q, n);
}

// ---------------- pre-linear (fp16 A, K=192 stride 192) + att dots ------------
__global__ __launch_bounds__(256) void k_pre16(const __half* __restrict__ A,
                                               const __half* __restrict__ Wf,
                                               const float* __restrict__ b,
                                               const float* __restrict__ attf,
                                               float* __restrict__ a_src,
                                               float* __restrict__ a_dst,
                                               __half* __restrict__ out) {
    int lane = threadIdx.x & 63, wv = threadIdx.x >> 6;
    int q = lane >> 4, n = lane & 15;
    int rowb = blockIdx.x * 64 + wv * 16;
    int rowA = rowb + n; if (rowA > NN - 1) rowA = NN - 1;
    floatx4 acc[4] = {};
    const __half* ap = A + (size_t)rowA * 192 + q * 8;
    const __half* wp = Wf + q * 128 + n * 8;
    #pragma unroll
    for (int kc = 0; kc < 6; ++kc) {
        half8 a = *(const half8*)(ap + kc * 32);
        #pragma unroll
        for (int t = 0; t < 4; ++t) {
            half8 bf = *(const half8*)(wp + (size_t)(kc * 4 + t) * 512);
            acc[t] = mfma16(a, bf, acc[t]);
        }
    }
    pre_epi(acc, b, attf, a_src, a_dst, out, rowb, q, n);
}

// ---------------- post-aggregation block-diag GEMM: agg[N,192] -> xout[N,192] -
// A row = {g0(64) | g1(64) | sg(64)}; out cols 0..127 = gat heads, 128..191 = sg
__global__ __launch_bounds__(256) void k_post(const __half* __restrict__ A,
                                              const __half* __restrict__ Wf,
                                              const float* __restrict__ gat_b,
                                              const float* __restrict__ sg_b,
                                              __half* __restrict__ out) {
    int lane = threadIdx.x & 63, wv = threadIdx.x >> 6;
    int q = lane >> 4, n = lane & 15;
    int rowb = blockIdx.x * 64 + wv * 16;
    int rowA = rowb + n; if (rowA > NN - 1) rowA = NN - 1;
    floatx4 acc[12] = {};
    const __half* ap = A + (size_t)rowA * 192 + q * 8;
    const __half* wp = Wf + q * 128 + n * 8;
    #pragma unroll
    for (int g = 0; g < 3; ++g) {
        #pragma unroll
        for (int kc = 0; kc < 2; ++kc) {
            half8 a = *(const half8*)(ap + g * 64 + kc * 32);
            #pragma unroll
            for (int tt = 0; tt < 4; ++tt) {
                int t = g * 4 + tt;
                half8 bf = *(const half8*)(wp + (size_t)(kc * 12 + t) * 512);
                acc[t] = mfma16(a, bf, acc[t]);
            }
        }
    }
    #pragma unroll
    for (int t = 0; t < 12; ++t) {
        float bb = (t < 8) ? gat_b[t * 16 + n] : sg_b[(t - 8) * 16 + n];
        #pragma unroll
        for (int r = 0; r < 4; ++r) {
            int row = rowb + q * 4 + r;
            if (row < NN)
                out[(size_t)row * 192 + t * 16 + n] =
                    __float2half(fmaxf(acc[t][r] + bb, 0.f));
        }
    }
}

// ---------------- classifier + log_softmax (MFMA, NT=2) -----------------------
__global__ __launch_bounds__(256) void k_clsm(const __half* __restrict__ A,
                                              const __half* __restrict__ Wf,
                                              const float* __restrict__ b,
                                              float* __restrict__ out) {
    int lane = threadIdx.x & 63, wv = threadIdx.x >> 6;
    int q = lane >> 4, n = lane & 15;
    int rowb = blockIdx.x * 64 + wv * 16;
    int rowA = rowb + n; if (rowA > NN - 1) rowA = NN - 1;
    floatx4 acc[2] = {};
    const __half* ap = A + (size_t)rowA * 192 + q * 8;
    const __half* wp = Wf + q * 128 + n * 8;
    #pragma unroll
    for (int kc = 0; kc < 6; ++kc) {
        half8 a = *(const half8*)(ap + kc * 32);
        #pragma unroll
        for (int t = 0; t < 2; ++t) {
            half8 bf = *(const half8*)(wp + (size_t)(kc * 2 + t) * 512);
            acc[t] = mfma16(a, bf, acc[t]);
        }
    }
    float b0 = b[n], b1 = b[16 + n];
    #pragma unroll
    for (int r = 0; r < 4; ++r) {
        float v0 = acc[0][r] + b0, v1 = acc[1][r] + b1;
        float mx = fmaxf(v0, v1);
        #pragma unroll
        for (int off = 1; off < 16; off <<= 1) mx = fmaxf(mx, __shfl_xor(mx, off));
        float sm = __expf(v0 - mx) + __expf(v1 - mx);
        #pragma unroll
        for (int off = 1; off < 16; off <<= 1) sm += __shfl_xor(sm, off);
        float lg = mx + __logf(sm);
        int row = rowb + q * 4 + r;
        if (row < NN) {
            out[(size_t)row * 32 + n]      = v0 - lg;
            out[(size_t)row * 32 + 16 + n] = v1 - lg;
        }
    }
}

// ---------------- fused GAT + SG aggregation in xh-space (64-wide) ------------
// one wave per dst; two half-waves each handle one edge (half2 per lane).
// per-edge scalars staged in LDS as float4 {al0, al1, wq, bits(src*128)}.
__global__ __launch_bounds__(256) void k_agg(const int* __restrict__ row_ptr,
                                             const int2* __restrict__ recs,
                                             const float* __restrict__ dinv,
                                             const float* __restrict__ a_src,
                                             const float* __restrict__ a_dst,
                                             const __half* __restrict__ xh,
                                             __half* __restrict__ agg) {
    __shared__ float4 einfo[4][64];
    int lane = threadIdx.x & 63;
    int wv = threadIdx.x >> 6;
    int d = blockIdx.x * 4 + wv;
    if (d >= NN) return;
    int p0 = row_ptr[d], p1 = row_ptr[d + 1];
    int nn = p1 - p0;
    float2 ad2 = ((const float2*)a_dst)[d];
    int sub = lane >> 5;
    unsigned flb = (unsigned)(lane & 31) * 4u;   // byte offset of this lane's half2

    float g00 = 0.f, g01 = 0.f;   // head0 agg, features (2fl, 2fl+1)
    float g10 = 0.f, g11 = 0.f;   // head1 agg
    float s0a = 0.f, s1a = 0.f;   // sg agg

#define EDGE_ACC(E) do {                                                        \
        unsigned off_ = (unsigned)__float_as_int((E).w) + flb;                  \
        float2 v_ = __half22float2(*(const __half2*)((const char*)xh + off_));  \
        g00 = fmaf((E).x, v_.x, g00); g01 = fmaf((E).x, v_.y, g01);             \
        g10 = fmaf((E).y, v_.x, g10); g11 = fmaf((E).y, v_.y, g11);             \
        s0a = fmaf((E).z, v_.x, s0a); s1a = fmaf((E).z, v_.y, s1a);             \
    } while (0)

    if (nn <= 64) {
        // ---- fast path (max degree ~40 for this graph) ----
        float v0 = -INFINITY, v1 = -INFINITY, ewq = 0.f; int es = 0;
        if (lane < nn) {
            int2 rec = recs[p0 + lane];
            es = rec.x;
            ewq = __int_as_float(rec.y);
            float2 a2 = ((const float2*)a_src)[es];
            v0 = a2.x + ad2.x; v0 = (v0 > 0.f) ? v0 : 0.2f * v0;
            v1 = a2.y + ad2.y; v1 = (v1 > 0.f) ? v1 : 0.2f * v1;
        }
        float m0 = v0, m1 = v1;
        #pragma unroll
        for (int off = 32; off; off >>= 1) {
            m0 = fmaxf(m0, __shfl_xor(m0, off));
            m1 = fmaxf(m1, __shfl_xor(m1, off));
        }
        float e0 = (lane < nn) ? __expf(v0 - m0) : 0.f;
        float e1 = (lane < nn) ? __expf(v1 - m1) : 0.f;
        float s0 = e0, s1 = e1;
        #pragma unroll
        for (int off = 32; off; off >>= 1) {
            s0 += __shfl_xor(s0, off);
            s1 += __shfl_xor(s1, off);
        }
        if (lane < nn)
            einfo[wv][lane] = make_float4(e0 / (s0 + 1e-16f), e1 / (s1 + 1e-16f),
                                          ewq, __int_as_float(es << 7));
        // intra-wave LDS: DS pipe is in-order per wave, no barrier needed
        const float4* ep = &einfo[wv][sub];
        int j = 0;
        for (; j + 4 <= nn; j += 4) {
            float4 eA = ep[j];
            float4 eB = ep[j + 2];
            EDGE_ACC(eA);
            EDGE_ACC(eB);
        }
        for (; j + 2 <= nn; j += 2) {
            float4 eA = ep[j];
            EDGE_ACC(eA);
        }
        if (nn & 1) {
            if (sub == 0) {
                float4 eT = einfo[wv][nn - 1];
                EDGE_ACC(eT);
            }
        }
    } else {
        // ---- generic 3-pass path (degree > 64; dead for this graph) ----
        float m0 = -INFINITY, m1 = -INFINITY;
        for (int e = p0 + lane; e < p1; e += 64) {
            int s = recs[e].x;
            float2 a2 = ((const float2*)a_src)[s];
            float v0 = a2.x + ad2.x; v0 = (v0 > 0.f) ? v0 : 0.2f * v0;
            float v1 = a2.y + ad2.y; v1 = (v1 > 0.f) ? v1 : 0.2f * v1;
            m0 = fmaxf(m0, v0); m1 = fmaxf(m1, v1);
        }
        #pragma unroll
        for (int off = 32; off; off >>= 1) {
            m0 = fmaxf(m0, __shfl_xor(m0, off));
            m1 = fmaxf(m1, __shfl_xor(m1, off));
        }
        float s0 = 0.f, s1 = 0.f;
        for (int e = p0 + lane; e < p1; e += 64) {
            int s = recs[e].x;
            float2 a2 = ((const float2*)a_src)[s];
            float v0 = a2.x + ad2.x; v0 = (v0 > 0.f) ? v0 : 0.2f * v0;
            float v1 = a2.y + ad2.y; v1 = (v1 > 0.f) ? v1 : 0.2f * v1;
            s0 += __expf(v0 - m0); s1 += __expf(v1 - m1);
        }
        #pragma unroll
        for (int off = 32; off; off >>= 1) {
            s0 += __shfl_xor(s0, off);
            s1 += __shfl_xor(s1, off);
        }
        float inv0 = 1.f / (s0 + 1e-16f), inv1 = 1.f / (s1 + 1e-16f);
        for (int base = p0; base < p1; base += 64) {
            int e = base + lane;
            int nc = min(64, p1 - base);
            if (e < p1) {
                int2 rec = recs[e];
                int es = rec.x;
                float ewq = __int_as_float(rec.y);
                float2 a2 = ((const float2*)a_src)[es];
                float v0 = a2.x + ad2.x; v0 = (v0 > 0.f) ? v0 : 0.2f * v0;
                float v1 = a2.y + ad2.y; v1 = (v1 > 0.f) ? v1 : 0.2f * v1;
                einfo[wv][lane] = make_float4(__expf(v0 - m0) * inv0,
                                              __expf(v1 - m1) * inv1,
                                              ewq, __int_as_float(es << 7));
            }
            const float4* ep = &einfo[wv][sub];
            int j = 0;
            for (; j + 2 <= nc; j += 2) {
                float4 eA = ep[j];
                EDGE_ACC(eA);
            }
            if (nc & 1) {
                if (sub == 0) {
                    float4 eT = einfo[wv][nc - 1];
                    EDGE_ACC(eT);
                }
            }
        }
    }
#undef EDGE_ACC

    // combine the two half-wave partial sums
    g00 += __shfl_xor(g00, 32); g01 += __shfl_xor(g01, 32);
    g10 += __shfl_xor(g10, 32); g11 += __shfl_xor(g11, 32);
    s0a += __shfl_xor(s0a, 32); s1a += __shfl_xor(s1a, 32);

    float did = dinv[d];
    __half* op = agg + (size_t)d * 192;
    int fp = (lane & 31) * 2;
    if (lane < 32) {
        *(__half2*)(op + fp)       = __floats2half2_rn(g00, g01);
        *(__half2*)(op + 128 + fp) = __floats2half2_rn(s0a * did, s1a * did);
    } else {
        *(__half2*)(op + 64 + fp)  = __floats2half2_rn(g10, g11);
    }
}

// ------------------------------------------------------------------------------
extern "C" void kernel_launch(void* const* d_in, const int* in_sizes, int n_in,
                              void* d_out, int out_size, void* d_ws, size_t ws_size,
                              hipStream_t stream) {
    const float* x   = (const float*)d_in[0];
    const int*   ei  = (const int*)d_in[1];
    const float* ew  = (const float*)d_in[2];
    const int* src = ei;
    const int* dst = ei + NE;

    const float* P[2][8];
    for (int l = 0; l < 2; ++l)
        for (int j = 0; j < 8; ++j)
            P[l][j] = (const float*)d_in[3 + l * 8 + j];
    const float* cls_W = (const float*)d_in[19];
    const float* cls_b = (const float*)d_in[20];

    float* ws = (float*)d_ws;
    const size_t n = NN;
    __half* xh_h = (__half*)(ws);             // [NN][64]  halves = 32N fl
    __half* agg  = (__half*)(ws + 32 * n);    // [NN][192] halves = 96N fl
    float* a_src = ws + 128 * n;              // 2N
    float* a_dst = ws + 130 * n;              // 2N
    __half* xA_h = (__half*)(ws + 132 * n);   // [NN][192] halves = 96N fl
    __half* xB_h = (__half*)(ws + 228 * n);   // [NN][192] halves = 96N fl
    __half* Wf   = (__half*)(ws + 324 * n);   // 59392 halves = 29696 fl
    float* attf  = ws + 324 * n + 29696;      // 512 fl (folded att vectors)
    float* base2 = ws + 324 * n + 29696 + 512;
    unsigned long long* packed = (unsigned long long*)base2;  // NN u64
    int*   cur        = (int*)(packed + NN);            // NN
    float* dinv       = (float*)(cur + NN);             // NN
    int*   row_ptr    = (int*)(dinv + NN);              // NN+1
    int*   bsum       = row_ptr + (NN + 1);             // 512
    int2*  recs       = (int2*)(bsum + 513);            // NES

    __half* Wf_pre0 = Wf;
    __half* Wf_pre1 = Wf + 16384;
    __half* Wf_pq0  = Wf + 28672;
    __half* Wf_pq1  = Wf + 40960;
    __half* Wf_cls  = Wf + 53248;

    const int TB = 256;
    int gb_edge  = (NES + TB - 1) / TB;
    int gb_node  = (NN + TB - 1) / TB;
    int gb_wave4 = (NN + 3) / 4;
    int gb64     = (NN + 63) / 64;

    // ---- all W pre-swizzles + folded attention vectors in one dispatch ----
    k_wconvall<<<(59904 + TB - 1) / TB, TB, 0, stream>>>(
        P[0][0], P[1][0], P[0][2], P[0][6], P[1][2], P[1][6], cls_W,
        P[0][3], P[0][4], P[1][3], P[1][4], Wf, attf);

    // ---- CSR build + degrees: packed u64 histogram ----
    hipMemsetAsync(packed, 0, NN * sizeof(unsigned long long), stream);
    k_histdeg<<<gb_edge, TB, 0, stream>>>(dst, ew, packed);
    k_scanA<<<NBLK, TB, 0, stream>>>(packed, row_ptr, bsum, dinv, cur);
    k_scanB<<<1, 512, 0, stream>>>(bsum);
    k_scanC<<<gb_node, TB, 0, stream>>>(row_ptr, bsum);
    k_fill <<<gb_edge, TB, 0, stream>>>(src, dst, ew, row_ptr, cur, dinv, recs);

    for (int l = 0; l < 2; ++l) {
        const float* pre_b = P[l][1];
        const float* gat_b = P[l][5];
        const float* sg_b  = P[l][7];
        __half* xout = (l == 0) ? xA_h : xB_h;

        if (l == 0)
            k_pre32<256><<<gb64, TB, 0, stream>>>(x, Wf_pre0, pre_b,
                                                  attf, a_src, a_dst, xh_h);
        else
            k_pre16<<<gb64, TB, 0, stream>>>(xA_h, Wf_pre1, pre_b,
                                             attf + 256, a_src, a_dst, xh_h);
        k_agg <<<gb_wave4, TB, 0, stream>>>(row_ptr, recs, dinv,
                                            a_src, a_dst, xh_h, agg);
        k_post<<<gb64, TB, 0, stream>>>(agg, (l == 0) ? Wf_pq0 : Wf_pq1,
                                        gat_b, sg_b, xout);
    }

    k_clsm<<<gb64, TB, 0, stream>>>(xB_h, Wf_cls, cls_b, (float*)d_out);
}

// Round 2
// 501.883 us; speedup vs baseline: 1.1240x; 1.0720x over previous
//
#include <hip/hip_runtime.h>
#include <hip/hip_fp16.h>
#include <math.h>

#define NN 100000
#define NE 1200000
#define FIN 256
#define NBLK 391        // (NN + 255) / 256
#define HB 4688         // (NE + 255) / 256  -- histdeg blocks in k_prep

using half8   = __attribute__((ext_vector_type(8))) _Float16;
using floatx4 = __attribute__((ext_vector_type(4))) float;

__device__ __forceinline__ floatx4 mfma16(half8 a, half8 b, floatx4 c) {
    return __builtin_amdgcn_mfma_f32_16x16x32_f16(a, b, c, 0, 0, 0);
}

// ---------------- fused: W pre-swizzle + folded att + histogram/ordinal -------
// packed[d]: bits[48:63] = count, bits[0:47] = sum(w) in 2^-32 fixed point.
// atomicAdd return captures this edge's within-dst ordinal -> ord[e] (coalesced).
// Self-loops are VIRTUAL (handled analytically in scanA/k_agg) — only NE edges.
__global__ __launch_bounds__(256) void k_prep(const int* __restrict__ dst,
                                              const float* __restrict__ ew,
                                              unsigned long long* __restrict__ packed,
                                              int* __restrict__ ord,
                                              const float* __restrict__ W0,
                                              const float* __restrict__ W1,
                                              const float* __restrict__ Wg0,
                                              const float* __restrict__ Ws0,
                                              const float* __restrict__ Wg1,
                                              const float* __restrict__ Ws1,
                                              const float* __restrict__ Wc,
                                              const float* __restrict__ As0,
                                              const float* __restrict__ Ad0,
                                              const float* __restrict__ As1,
                                              const float* __restrict__ Ad1,
                                              __half* __restrict__ Wf,
                                              float* __restrict__ attf) {
    int bid = blockIdx.x;
    if (bid < HB) {
        int e = bid * 256 + threadIdx.x;
        if (e >= NE) return;
        int d = dst[e]; float w = ew[e];
        unsigned long long add = (1ULL << 48)
            + (unsigned long long)((double)w * 4294967296.0);
        unsigned long long old = atomicAdd(&packed[d], add);
        ord[e] = (int)(old >> 48);
        return;
    }
    int o = (bid - HB) * 256 + threadIdx.x;
    if (o >= 59904) return;
    if (o >= 59392) {
        // folded attention vectors: attf_v[c] = sum_j gat_W[c, h*64+j] * att[h, j]
        int idx = o - 59392;          // 0..511
        int layer = idx >> 8, rem = idx & 255;
        int v = rem >> 6, c = rem & 63, h = v & 1;
        const float* Wg = layer ? Wg1 : Wg0;
        const float* av = (v < 2) ? (layer ? As1 : As0) : (layer ? Ad1 : Ad0);
        float s = 0.f;
        for (int jj = 0; jj < 64; ++jj)
            s = fmaf(Wg[c * 128 + h * 64 + jj], av[h * 64 + jj], s);
        attf[idx] = s;
        return;
    }
    int lo, NT, N; const float* Wg; const float* Wsg = nullptr;
    if (o < 16384)      { lo = o;         NT = 4;  N = 64; Wg = W0; }
    else if (o < 28672) { lo = o - 16384; NT = 4;  N = 64; Wg = W1; }
    else if (o < 40960) { lo = o - 28672; NT = 12; N = 0;  Wg = Wg0; Wsg = Ws0; }
    else if (o < 53248) { lo = o - 40960; NT = 12; N = 0;  Wg = Wg1; Wsg = Ws1; }
    else                { lo = o - 53248; NT = 2;  N = 32; Wg = Wc; }
    int j = lo & 7, n = (lo >> 3) & 15, q = (lo >> 7) & 3, rest = lo >> 9;
    int t = rest % NT, kc = rest / NT;
    int k = kc * 32 + q * 8 + j, col = t * 16 + n;
    float v;
    if (Wsg) v = (col < 128) ? Wg[(size_t)k * 128 + col] : Wsg[(size_t)k * 64 + (col - 128)];
    else     v = Wg[(size_t)k * N + col];
    Wf[o] = __float2half(v);
}

// ---------------- CSR scan (+ unpack, dinv incl. self-loop) -------------------
__global__ __launch_bounds__(256) void k_scanA(const unsigned long long* __restrict__ packed,
                                               int* __restrict__ row_ptr,
                                               int* __restrict__ bsum,
                                               float* __restrict__ asd) {
    __shared__ int tmp[256];
    int tid = threadIdx.x;
    int i = blockIdx.x * 256 + tid;
    int v = 0;
    if (i < NN) {
        unsigned long long p = packed[i];
        v = (int)(p >> 48);
        // +1.0 = virtual self-loop weight; deg >= 1 always
        double deg = (double)(p & 0xFFFFFFFFFFFFULL) * (1.0 / 4294967296.0) + 1.0;
        asd[i * 4 + 2] = rsqrtf((float)deg);
    }
    tmp[tid] = v;
    __syncthreads();
    for (int off = 1; off < 256; off <<= 1) {
        int t = (tid >= off) ? tmp[tid - off] : 0;
        __syncthreads();
        tmp[tid] += t;
        __syncthreads();
    }
    if (i < NN) row_ptr[i] = tmp[tid] - v;
    if (tid == 255) bsum[blockIdx.x] = tmp[255];
}

__global__ __launch_bounds__(512) void k_scanB(int* __restrict__ bsum) {
    __shared__ int tmp[512];
    int tid = threadIdx.x;
    int v = (tid < NBLK) ? bsum[tid] : 0;
    tmp[tid] = v;
    __syncthreads();
    for (int off = 1; off < 512; off <<= 1) {
        int t = (tid >= off) ? tmp[tid - off] : 0;
        __syncthreads();
        tmp[tid] += t;
        __syncthreads();
    }
    if (tid < NBLK) bsum[tid] = tmp[tid] - v;
}

__global__ __launch_bounds__(256) void k_scanC(int* __restrict__ row_ptr,
                                               const int* __restrict__ bsum) {
    int i = blockIdx.x * 256 + threadIdx.x;
    if (i < NN) row_ptr[i] += bsum[i >> 8];
    if (i == 0) row_ptr[NN] = NE;
}

// ---------------- CSR fill: NO atomic, NO dinv gather -------------------------
// pos = row_ptr[dst] + precomputed ordinal; record = {src, raw w}
__global__ __launch_bounds__(256) void k_fill(const int* __restrict__ src,
                                              const int* __restrict__ dst,
                                              const float* __restrict__ ew,
                                              const int* __restrict__ row_ptr,
                                              const int* __restrict__ ord,
                                              int2* __restrict__ recs) {
    int e = blockIdx.x * 256 + threadIdx.x;
    if (e >= NE) return;
    int d = dst[e];
    int pos = row_ptr[d] + ord[e];
    int2 r; r.x = src[e]; r.y = __float_as_int(ew[e]);
    recs[pos] = r;
}

// ---------------- shared epilogue for pre-linear: store xh + att dots ---------
// asd row = {a_src0, a_src1, dinv, pad} (dinv written by scanA, untouched here)
__device__ __forceinline__ void pre_epi(floatx4* acc, const float* b, const float* attf,
                                        float* asd, float* a_dst, __half* out,
                                        int rowb, int q, int n) {
    float vs0[4] = {0,0,0,0}, vs1[4] = {0,0,0,0};
    float vd0[4] = {0,0,0,0}, vd1[4] = {0,0,0,0};
    #pragma unroll
    for (int t = 0; t < 4; ++t) {
        float bb  = b[t * 16 + n];
        float ws0 = attf[t * 16 + n],       ws1 = attf[64 + t * 16 + n];
        float wd0 = attf[128 + t * 16 + n], wd1 = attf[192 + t * 16 + n];
        #pragma unroll
        for (int r = 0; r < 4; ++r) {
            float xv = acc[t][r] + bb;
            int row = rowb + q * 4 + r;
            if (row < NN) out[(size_t)row * 64 + t * 16 + n] = __float2half(xv);
            vs0[r] = fmaf(xv, ws0, vs0[r]);
            vs1[r] = fmaf(xv, ws1, vs1[r]);
            vd0[r] = fmaf(xv, wd0, vd0[r]);
            vd1[r] = fmaf(xv, wd1, vd1[r]);
        }
    }
    #pragma unroll
    for (int off = 1; off < 16; off <<= 1) {
        #pragma unroll
        for (int r = 0; r < 4; ++r) {
            vs0[r] += __shfl_xor(vs0[r], off);
            vs1[r] += __shfl_xor(vs1[r], off);
            vd0[r] += __shfl_xor(vd0[r], off);
            vd1[r] += __shfl_xor(vd1[r], off);
        }
    }
    if (n == 0) {
        #pragma unroll
        for (int r = 0; r < 4; ++r) {
            int row = rowb + q * 4 + r;
            if (row < NN) {
                *(float2*)&asd[row * 4] = make_float2(vs0[r], vs1[r]);
                *(float2*)&a_dst[row * 2] = make_float2(vd0[r], vd1[r]);
            }
        }
    }
}

// ---------------- pre-linear (fp32 A): xh = x @ W[K,64] + b -> fp16 + att dots
template<int KK>
__global__ __launch_bounds__(256) void k_pre32(const float* __restrict__ A,
                                               const __half* __restrict__ Wf,
                                               const float* __restrict__ b,
                                               const float* __restrict__ attf,
                                               float* __restrict__ asd,
                                               float* __restrict__ a_dst,
                                               __half* __restrict__ out) {
    int lane = threadIdx.x & 63, wv = threadIdx.x >> 6;
    int q = lane >> 4, n = lane & 15;
    int rowb = blockIdx.x * 64 + wv * 16;
    int rowA = rowb + n; if (rowA > NN - 1) rowA = NN - 1;
    floatx4 acc[4] = {};
    const float* ap = A + (size_t)rowA * KK + q * 8;
    const __half* wp = Wf + q * 128 + n * 8;
    #pragma unroll
    for (int kc = 0; kc < KK / 32; ++kc) {
        float4 f0 = *(const float4*)(ap + kc * 32);
        float4 f1 = *(const float4*)(ap + kc * 32 + 4);
        half8 a;
        a[0] = (_Float16)f0.x; a[1] = (_Float16)f0.y;
        a[2] = (_Float16)f0.z; a[3] = (_Float16)f0.w;
        a[4] = (_Float16)f1.x; a[5] = (_Float16)f1.y;
        a[6] = (_Float16)f1.z; a[7] = (_Float16)f1.w;
        #pragma unroll
        for (int t = 0; t < 4; ++t) {
            half8 bf = *(const half8*)(wp + (size_t)(kc * 4 + t) * 512);
            acc[t] = mfma16(a, bf, acc[t]);
        }
    }
    pre_epi(acc, b, attf, asd, a_dst, out, rowb, q, n);
}

// ---------------- pre-linear (fp16 A, K=192 stride 192) + att dots ------------
__global__ __launch_bounds__(256) void k_pre16(const __half* __restrict__ A,
                                               const __half* __restrict__ Wf,
                                               const float* __restrict__ b,
                                               const float* __restrict__ attf,
                                               float* __restrict__ asd,
                                               float* __restrict__ a_dst,
                                               __half* __restrict__ out) {
    int lane = threadIdx.x & 63, wv = threadIdx.x >> 6;
    int q = lane >> 4, n = lane & 15;
    int rowb = blockIdx.x * 64 + wv * 16;
    int rowA = rowb + n; if (rowA > NN - 1) rowA = NN - 1;
    floatx4 acc[4] = {};
    const __half* ap = A + (size_t)rowA * 192 + q * 8;
    const __half* wp = Wf + q * 128 + n * 8;
    #pragma unroll
    for (int kc = 0; kc < 6; ++kc) {
        half8 a = *(const half8*)(ap + kc * 32);
        #pragma unroll
        for (int t = 0; t < 4; ++t) {
            half8 bf = *(const half8*)(wp + (size_t)(kc * 4 + t) * 512);
            acc[t] = mfma16(a, bf, acc[t]);
        }
    }
    pre_epi(acc, b, attf, asd, a_dst, out, rowb, q, n);
}

// ---------------- post-aggregation block-diag GEMM: agg[N,192] -> xout[N,192] -
__global__ __launch_bounds__(256) void k_post(const __half* __restrict__ A,
                                              const __half* __restrict__ Wf,
                                              const float* __restrict__ gat_b,
                                              const float* __restrict__ sg_b,
                                              __half* __restrict__ out) {
    int lane = threadIdx.x & 63, wv = threadIdx.x >> 6;
    int q = lane >> 4, n = lane & 15;
    int rowb = blockIdx.x * 64 + wv * 16;
    int rowA = rowb + n; if (rowA > NN - 1) rowA = NN - 1;
    floatx4 acc[12] = {};
    const __half* ap = A + (size_t)rowA * 192 + q * 8;
    const __half* wp = Wf + q * 128 + n * 8;
    #pragma unroll
    for (int g = 0; g < 3; ++g) {
        #pragma unroll
        for (int kc = 0; kc < 2; ++kc) {
            half8 a = *(const half8*)(ap + g * 64 + kc * 32);
            #pragma unroll
            for (int tt = 0; tt < 4; ++tt) {
                int t = g * 4 + tt;
                half8 bf = *(const half8*)(wp + (size_t)(kc * 12 + t) * 512);
                acc[t] = mfma16(a, bf, acc[t]);
            }
        }
    }
    #pragma unroll
    for (int t = 0; t < 12; ++t) {
        float bb = (t < 8) ? gat_b[t * 16 + n] : sg_b[(t - 8) * 16 + n];
        #pragma unroll
        for (int r = 0; r < 4; ++r) {
            int row = rowb + q * 4 + r;
            if (row < NN)
                out[(size_t)row * 192 + t * 16 + n] =
                    __float2half(fmaxf(acc[t][r] + bb, 0.f));
        }
    }
}

// ---------------- classifier + log_softmax (MFMA, NT=2) -----------------------
__global__ __launch_bounds__(256) void k_clsm(const __half* __restrict__ A,
                                              const __half* __restrict__ Wf,
                                              const float* __restrict__ b,
                                              float* __restrict__ out) {
    int lane = threadIdx.x & 63, wv = threadIdx.x >> 6;
    int q = lane >> 4, n = lane & 15;
    int rowb = blockIdx.x * 64 + wv * 16;
    int rowA = rowb + n; if (rowA > NN - 1) rowA = NN - 1;
    floatx4 acc[2] = {};
    const __half* ap = A + (size_t)rowA * 192 + q * 8;
    const __half* wp = Wf + q * 128 + n * 8;
    #pragma unroll
    for (int kc = 0; kc < 6; ++kc) {
        half8 a = *(const half8*)(ap + kc * 32);
        #pragma unroll
        for (int t = 0; t < 2; ++t) {
            half8 bf = *(const half8*)(wp + (size_t)(kc * 2 + t) * 512);
            acc[t] = mfma16(a, bf, acc[t]);
        }
    }
    float b0 = b[n], b1 = b[16 + n];
    #pragma unroll
    for (int r = 0; r < 4; ++r) {
        float v0 = acc[0][r] + b0, v1 = acc[1][r] + b1;
        float mx = fmaxf(v0, v1);
        #pragma unroll
        for (int off = 1; off < 16; off <<= 1) mx = fmaxf(mx, __shfl_xor(mx, off));
        float sm = __expf(v0 - mx) + __expf(v1 - mx);
        #pragma unroll
        for (int off = 1; off < 16; off <<= 1) sm += __shfl_xor(sm, off);
        float lg = mx + __logf(sm);
        int row = rowb + q * 4 + r;
        if (row < NN) {
            out[(size_t)row * 32 + n]      = v0 - lg;
            out[(size_t)row * 32 + 16 + n] = v1 - lg;
        }
    }
}

// ---------------- fused GAT + SG aggregation in xh-space (64-wide) ------------
// one wave per dst; two half-waves each handle one edge (half2 per lane).
// Virtual self-loop appended at lane nn. asd gather = {as0, as1, dinv_src}.
__global__ __launch_bounds__(256) void k_agg(const int* __restrict__ row_ptr,
                                             const int2* __restrict__ recs,
                                             const float* __restrict__ asd,
                                             const float* __restrict__ a_dst,
                                             const __half* __restrict__ xh,
                                             __half* __restrict__ agg) {
    __shared__ float4 einfo[4][64];
    int lane = threadIdx.x & 63;
    int wv = threadIdx.x >> 6;
    int d = blockIdx.x * 4 + wv;
    if (d >= NN) return;
    int p0 = row_ptr[d], p1 = row_ptr[d + 1];
    int nn = p1 - p0;                 // real edges; +1 virtual self-loop
    float2 ad2 = ((const float2*)a_dst)[d];
    const float4* asd4 = (const float4*)asd;
    int sub = lane >> 5;
    unsigned flb = (unsigned)(lane & 31) * 4u;   // byte offset of this lane's half2

    float g00 = 0.f, g01 = 0.f;   // head0 agg
    float g10 = 0.f, g11 = 0.f;   // head1 agg
    float s0a = 0.f, s1a = 0.f;   // sg agg

#define EDGE_ACC(E) do {                                                        \
        unsigned off_ = (unsigned)__float_as_int((E).w) + flb;                  \
        float2 v_ = __half22float2(*(const __half2*)((const char*)xh + off_));  \
        g00 = fmaf((E).x, v_.x, g00); g01 = fmaf((E).x, v_.y, g01);             \
        g10 = fmaf((E).y, v_.x, g10); g11 = fmaf((E).y, v_.y, g11);             \
        s0a = fmaf((E).z, v_.x, s0a); s1a = fmaf((E).z, v_.y, s1a);             \
    } while (0)

    if (nn <= 63) {
        // ---- fast path (max degree ~40 for this graph) ----
        int tot = nn + 1;
        float v0 = -INFINITY, v1 = -INFINITY, ewq = 0.f; int es = 0;
        if (lane < tot) {
            float wraw;
            if (lane < nn) {
                int2 rec = recs[p0 + lane];
                es = rec.x;
                wraw = __int_as_float(rec.y);
            } else { es = d; wraw = 1.f; }       // virtual self-loop
            float4 a4 = asd4[es];
            v0 = a4.x + ad2.x; v0 = (v0 > 0.f) ? v0 : 0.2f * v0;
            v1 = a4.y + ad2.y; v1 = (v1 > 0.f) ? v1 : 0.2f * v1;
            ewq = wraw * a4.z;                   // w * dinv[src]
        }
        float m0 = v0, m1 = v1;
        #pragma unroll
        for (int off = 32; off; off >>= 1) {
            m0 = fmaxf(m0, __shfl_xor(m0, off));
            m1 = fmaxf(m1, __shfl_xor(m1, off));
        }
        float e0 = (lane < tot) ? __expf(v0 - m0) : 0.f;
        float e1 = (lane < tot) ? __expf(v1 - m1) : 0.f;
        float s0 = e0, s1 = e1;
        #pragma unroll
        for (int off = 32; off; off >>= 1) {
            s0 += __shfl_xor(s0, off);
            s1 += __shfl_xor(s1, off);
        }
        if (lane < tot)
            einfo[wv][lane] = make_float4(e0 / (s0 + 1e-16f), e1 / (s1 + 1e-16f),
                                          ewq, __int_as_float(es << 7));
        // intra-wave LDS: DS pipe is in-order per wave, no barrier needed
        const float4* ep = &einfo[wv][sub];
        int j = 0;
        for (; j + 4 <= tot; j += 4) {
            float4 eA = ep[j];
            float4 eB = ep[j + 2];
            EDGE_ACC(eA);
            EDGE_ACC(eB);
        }
        for (; j + 2 <= tot; j += 2) {
            float4 eA = ep[j];
            EDGE_ACC(eA);
        }
        if (tot & 1) {
            if (sub == 0) {
                float4 eT = einfo[wv][tot - 1];
                EDGE_ACC(eT);
            }
        }
    } else {
        // ---- generic 3-pass path (degree > 63; dead for this graph) ----
        float4 aself = asd4[d];
        float sv0 = aself.x + ad2.x; sv0 = (sv0 > 0.f) ? sv0 : 0.2f * sv0;
        float sv1 = aself.y + ad2.y; sv1 = (sv1 > 0.f) ? sv1 : 0.2f * sv1;
        float m0 = sv0, m1 = sv1;
        for (int e = p0 + lane; e < p1; e += 64) {
            int s = recs[e].x;
            float4 a4 = asd4[s];
            float v0 = a4.x + ad2.x; v0 = (v0 > 0.f) ? v0 : 0.2f * v0;
            float v1 = a4.y + ad2.y; v1 = (v1 > 0.f) ? v1 : 0.2f * v1;
            m0 = fmaxf(m0, v0); m1 = fmaxf(m1, v1);
        }
        #pragma unroll
        for (int off = 32; off; off >>= 1) {
            m0 = fmaxf(m0, __shfl_xor(m0, off));
            m1 = fmaxf(m1, __shfl_xor(m1, off));
        }
        float s0 = 0.f, s1 = 0.f;
        for (int e = p0 + lane; e < p1; e += 64) {
            int s = recs[e].x;
            float4 a4 = asd4[s];
            float v0 = a4.x + ad2.x; v0 = (v0 > 0.f) ? v0 : 0.2f * v0;
            float v1 = a4.y + ad2.y; v1 = (v1 > 0.f) ? v1 : 0.2f * v1;
            s0 += __expf(v0 - m0); s1 += __expf(v1 - m1);
        }
        #pragma unroll
        for (int off = 32; off; off >>= 1) {
            s0 += __shfl_xor(s0, off);
            s1 += __shfl_xor(s1, off);
        }
        s0 += __expf(sv0 - m0); s1 += __expf(sv1 - m1);   // self contribution
        float inv0 = 1.f / (s0 + 1e-16f), inv1 = 1.f / (s1 + 1e-16f);
        for (int base = p0; base < p1; base += 64) {
            int e = base + lane;
            int nc = min(64, p1 - base);
            if (e < p1) {
                int2 rec = recs[e];
                int es = rec.x;
                float4 a4 = asd4[es];
                float v0 = a4.x + ad2.x; v0 = (v0 > 0.f) ? v0 : 0.2f * v0;
                float v1 = a4.y + ad2.y; v1 = (v1 > 0.f) ? v1 : 0.2f * v1;
                einfo[wv][lane] = make_float4(__expf(v0 - m0) * inv0,
                                              __expf(v1 - m1) * inv1,
                                              __int_as_float(rec.y) * a4.z,
                                              __int_as_float(es << 7));
            }
            const float4* ep = &einfo[wv][sub];
            int j = 0;
            for (; j + 2 <= nc; j += 2) {
                float4 eA = ep[j];
                EDGE_ACC(eA);
            }
            if (nc & 1) {
                if (sub == 0) {
                    float4 eT = einfo[wv][nc - 1];
                    EDGE_ACC(eT);
                }
            }
        }
        if (sub == 0) {   // virtual self-loop
            float4 eS = make_float4(__expf(sv0 - m0) * inv0,
                                    __expf(sv1 - m1) * inv1,
                                    aself.z, __int_as_float(d << 7));
            EDGE_ACC(eS);
        }
    }
#undef EDGE_ACC

    // combine the two half-wave partial sums
    g00 += __shfl_xor(g00, 32); g01 += __shfl_xor(g01, 32);
    g10 += __shfl_xor(g10, 32); g11 += __shfl_xor(g11, 32);
    s0a += __shfl_xor(s0a, 32); s1a += __shfl_xor(s1a, 32);

    float did = asd[d * 4 + 2];
    __half* op = agg + (size_t)d * 192;
    int fp = (lane & 31) * 2;
    if (lane < 32) {
        *(__half2*)(op + fp)       = __floats2half2_rn(g00, g01);
        *(__half2*)(op + 128 + fp) = __floats2half2_rn(s0a * did, s1a * did);
    } else {
        *(__half2*)(op + 64 + fp)  = __floats2half2_rn(g10, g11);
    }
}

// ------------------------------------------------------------------------------
extern "C" void kernel_launch(void* const* d_in, const int* in_sizes, int n_in,
                              void* d_out, int out_size, void* d_ws, size_t ws_size,
                              hipStream_t stream) {
    const float* x   = (const float*)d_in[0];
    const int*   ei  = (const int*)d_in[1];
    const float* ew  = (const float*)d_in[2];
    const int* src = ei;
    const int* dst = ei + NE;

    const float* P[2][8];
    for (int l = 0; l < 2; ++l)
        for (int j = 0; j < 8; ++j)
            P[l][j] = (const float*)d_in[3 + l * 8 + j];
    const float* cls_W = (const float*)d_in[19];
    const float* cls_b = (const float*)d_in[20];

    float* ws = (float*)d_ws;
    const size_t n = NN;
    __half* xh_h = (__half*)(ws);             // [NN][64]  halves = 32N fl
    __half* agg  = (__half*)(ws + 32 * n);    // [NN][192] halves = 96N fl
    float* asd   = ws + 128 * n;              // [NN]{as0,as1,dinv,pad} = 4N fl
    float* a_dst = ws + 132 * n;              // 2N
    __half* xA_h = (__half*)(ws + 134 * n);   // [NN][192] halves = 96N fl
    __half* xB_h = (__half*)(ws + 230 * n);   // [NN][192] halves = 96N fl
    __half* Wf   = (__half*)(ws + 326 * n);   // 59392 halves = 29696 fl
    float* attf  = ws + 326 * n + 29696;      // 512 fl (folded att vectors)
    float* base2 = ws + 326 * n + 30208;
    unsigned long long* packed = (unsigned long long*)base2;  // NN u64
    int*   row_ptr    = (int*)(packed + NN);            // NN+1
    int*   bsum       = row_ptr + (NN + 1);             // 513
    int*   ord        = bsum + 513;                     // NE
    int2*  recs       = (int2*)(ord + NE);              // NE (8B-aligned: even fl offset)

    __half* Wf_pre0 = Wf;
    __half* Wf_pre1 = Wf + 16384;
    __half* Wf_pq0  = Wf + 28672;
    __half* Wf_pq1  = Wf + 40960;
    __half* Wf_cls  = Wf + 53248;

    const int TB = 256;
    int gb_edge  = (NE + TB - 1) / TB;     // == HB
    int gb_node  = (NN + TB - 1) / TB;
    int gb_wave4 = (NN + 3) / 4;
    int gb64     = (NN + 63) / 64;

    // ---- histogram+ordinal fused with W pre-swizzles (independent work) ----
    hipMemsetAsync(packed, 0, NN * sizeof(unsigned long long), stream);
    k_prep<<<HB + (59904 + TB - 1) / TB, TB, 0, stream>>>(
        dst, ew, packed, ord,
        P[0][0], P[1][0], P[0][2], P[0][6], P[1][2], P[1][6], cls_W,
        P[0][3], P[0][4], P[1][3], P[1][4], Wf, attf);

    k_scanA<<<NBLK, TB, 0, stream>>>(packed, row_ptr, bsum, asd);
    k_scanB<<<1, 512, 0, stream>>>(bsum);
    k_scanC<<<gb_node, TB, 0, stream>>>(row_ptr, bsum);
    k_fill <<<gb_edge, TB, 0, stream>>>(src, dst, ew, row_ptr, ord, recs);

    for (int l = 0; l < 2; ++l) {
        const float* pre_b = P[l][1];
        const float* gat_b = P[l][5];
        const float* sg_b  = P[l][7];
        __half* xout = (l == 0) ? xA_h : xB_h;

        if (l == 0)
            k_pre32<256><<<gb64, TB, 0, stream>>>(x, Wf_pre0, pre_b,
                                                  attf, asd, a_dst, xh_h);
        else
            k_pre16<<<gb64, TB, 0, stream>>>(xA_h, Wf_pre1, pre_b,
                                             attf + 256, asd, a_dst, xh_h);
        k_agg <<<gb_wave4, TB, 0, stream>>>(row_ptr, recs, asd, a_dst, xh_h, agg);
        k_post<<<gb64, TB, 0, stream>>>(agg, (l == 0) ? Wf_pq0 : Wf_pq1,
                                        gat_b, sg_b, xout);
    }

    k_clsm<<<gb64, TB, 0, stream>>>(xB_h, Wf_cls, cls_b, (float*)d_out);
}

// Round 3
// 482.696 us; speedup vs baseline: 1.1686x; 1.0397x over previous
//
#include <hip/hip_runtime.h>
#include <hip/hip_fp16.h>
#include <math.h>

#define NN 100000
#define NE 1200000
#define FIN 256
#define NBLK 391        // (NN + 255) / 256
#define HB 4688         // (NE + 255) / 256  -- histdeg blocks in k_prep
#define WB 170          // (59904 - 16384) / 256 -- W-swizzle blocks (skip pre0 region)
#define GB64 1563       // (NN + 63) / 64  -- 64-row GEMM blocks

using half8   = __attribute__((ext_vector_type(8))) _Float16;
using floatx4 = __attribute__((ext_vector_type(4))) float;

__device__ __forceinline__ floatx4 mfma16(half8 a, half8 b, floatx4 c) {
    return __builtin_amdgcn_mfma_f32_16x16x32_f16(a, b, c, 0, 0, 0);
}

// ---------------- shared epilogue for pre-linear: store xh + att dots ---------
// asd row = {a_src0, a_src1, dinv, pad} (dinv written by k_scan, untouched here)
__device__ __forceinline__ void pre_epi(floatx4* acc, const float* b, const float* attf,
                                        float* asd, float* a_dst, __half* out,
                                        int rowb, int q, int n) {
    float vs0[4] = {0,0,0,0}, vs1[4] = {0,0,0,0};
    float vd0[4] = {0,0,0,0}, vd1[4] = {0,0,0,0};
    #pragma unroll
    for (int t = 0; t < 4; ++t) {
        float bb  = b[t * 16 + n];
        float ws0 = attf[t * 16 + n],       ws1 = attf[64 + t * 16 + n];
        float wd0 = attf[128 + t * 16 + n], wd1 = attf[192 + t * 16 + n];
        #pragma unroll
        for (int r = 0; r < 4; ++r) {
            float xv = acc[t][r] + bb;
            int row = rowb + q * 4 + r;
            if (row < NN) out[(size_t)row * 64 + t * 16 + n] = __float2half(xv);
            vs0[r] = fmaf(xv, ws0, vs0[r]);
            vs1[r] = fmaf(xv, ws1, vs1[r]);
            vd0[r] = fmaf(xv, wd0, vd0[r]);
            vd1[r] = fmaf(xv, wd1, vd1[r]);
        }
    }
    #pragma unroll
    for (int off = 1; off < 16; off <<= 1) {
        #pragma unroll
        for (int r = 0; r < 4; ++r) {
            vs0[r] += __shfl_xor(vs0[r], off);
            vs1[r] += __shfl_xor(vs1[r], off);
            vd0[r] += __shfl_xor(vd0[r], off);
            vd1[r] += __shfl_xor(vd1[r], off);
        }
    }
    if (n == 0) {
        #pragma unroll
        for (int r = 0; r < 4; ++r) {
            int row = rowb + q * 4 + r;
            if (row < NN) {
                *(float2*)&asd[row * 4] = make_float2(vs0[r], vs1[r]);
                *(float2*)&a_dst[row * 2] = make_float2(vd0[r], vd1[r]);
            }
        }
    }
}

// ---------------- mega-prep: histogram/ordinal | W swizzle+attf | pre32 -------
// packed[d]: bits[48:63] = count, bits[0:47] = sum(w) in 2^-32 fixed point.
// pre32 blocks convert W0 fp32->swizzled fp16 LDS + layer-0 att-fold in-block,
// so the x@W0 GEMM runs CONCURRENTLY with the edge histogram (indep. work).
__global__ __launch_bounds__(256) void k_prep(const int* __restrict__ dst,
                                              const float* __restrict__ ew,
                                              unsigned long long* __restrict__ packed,
                                              int* __restrict__ ord,
                                              const float* __restrict__ x,
                                              const float* __restrict__ W0,
                                              const float* __restrict__ W1,
                                              const float* __restrict__ Wg0,
                                              const float* __restrict__ Ws0,
                                              const float* __restrict__ Wg1,
                                              const float* __restrict__ Ws1,
                                              const float* __restrict__ Wc,
                                              const float* __restrict__ As0,
                                              const float* __restrict__ Ad0,
                                              const float* __restrict__ As1,
                                              const float* __restrict__ Ad1,
                                              const float* __restrict__ pre_b0,
                                              __half* __restrict__ Wf,
                                              float* __restrict__ attf,
                                              float* __restrict__ asd,
                                              float* __restrict__ a_dst,
                                              __half* __restrict__ xh) {
    __shared__ __half Wl[16384];
    __shared__ float attL[256];
    int bid = blockIdx.x;
    int tid = threadIdx.x;
    if (bid < HB) {
        // ---- edge histogram + ordinal capture ----
        int e = bid * 256 + tid;
        if (e >= NE) return;
        int d = dst[e]; float w = ew[e];
        unsigned long long add = (1ULL << 48)
            + (unsigned long long)((double)w * 4294967296.0);
        unsigned long long old = atomicAdd(&packed[d], add);
        ord[e] = (int)(old >> 48);
        return;
    }
    if (bid < HB + WB) {
        // ---- W swizzle (pre1, pq0, pq1, cls) + global folded att vectors ----
        int o = (bid - HB) * 256 + tid + 16384;
        if (o >= 59904) return;
        if (o >= 59392) {
            int idx = o - 59392;          // 0..511
            int layer = idx >> 8, rem = idx & 255;
            int v = rem >> 6, c = rem & 63, h = v & 1;
            const float* Wg = layer ? Wg1 : Wg0;
            const float* av = (v < 2) ? (layer ? As1 : As0) : (layer ? Ad1 : Ad0);
            float s = 0.f;
            for (int jj = 0; jj < 64; ++jj)
                s = fmaf(Wg[c * 128 + h * 64 + jj], av[h * 64 + jj], s);
            attf[idx] = s;
            return;
        }
        int lo, NT, N; const float* Wg; const float* Wsg = nullptr;
        if (o < 28672)      { lo = o - 16384; NT = 4;  N = 64; Wg = W1; }
        else if (o < 40960) { lo = o - 28672; NT = 12; N = 0;  Wg = Wg0; Wsg = Ws0; }
        else if (o < 53248) { lo = o - 40960; NT = 12; N = 0;  Wg = Wg1; Wsg = Ws1; }
        else                { lo = o - 53248; NT = 2;  N = 32; Wg = Wc; }
        int j = lo & 7, n = (lo >> 3) & 15, q = (lo >> 7) & 3, rest = lo >> 9;
        int t = rest % NT, kc = rest / NT;
        int k = kc * 32 + q * 8 + j, col = t * 16 + n;
        float v;
        if (Wsg) v = (col < 128) ? Wg[(size_t)k * 128 + col] : Wsg[(size_t)k * 64 + (col - 128)];
        else     v = Wg[(size_t)k * N + col];
        Wf[o] = __float2half(v);
        return;
    }
    // ---- pre32: xh = x @ W0 + b -> fp16, + layer-0 att dots ----
    int pb = bid - (HB + WB);
    for (int i = tid; i < 16384; i += 256) {
        int j = i & 7, n = (i >> 3) & 15, q = (i >> 7) & 3, rest = i >> 9;
        int t = rest & 3, kc = rest >> 2;
        int k = kc * 32 + q * 8 + j, col = t * 16 + n;
        Wl[i] = __float2half(W0[(size_t)k * 64 + col]);
    }
    {
        int v = tid >> 6, c = tid & 63, h = v & 1;
        const float* av = (v < 2) ? As0 : Ad0;
        float s = 0.f;
        for (int jj = 0; jj < 64; ++jj)
            s = fmaf(Wg0[c * 128 + h * 64 + jj], av[h * 64 + jj], s);
        attL[tid] = s;
    }
    __syncthreads();
    int lane = tid & 63, wvv = tid >> 6;
    int q = lane >> 4, n = lane & 15;
    int rowb = pb * 64 + wvv * 16;
    int rowA = rowb + n; if (rowA > NN - 1) rowA = NN - 1;
    floatx4 acc[4] = {};
    const float* ap = x + (size_t)rowA * FIN + q * 8;
    const __half* wp = Wl + q * 128 + n * 8;
    #pragma unroll
    for (int kc = 0; kc < FIN / 32; ++kc) {
        float4 f0 = *(const float4*)(ap + kc * 32);
        float4 f1 = *(const float4*)(ap + kc * 32 + 4);
        half8 a;
        a[0] = (_Float16)f0.x; a[1] = (_Float16)f0.y;
        a[2] = (_Float16)f0.z; a[3] = (_Float16)f0.w;
        a[4] = (_Float16)f1.x; a[5] = (_Float16)f1.y;
        a[6] = (_Float16)f1.z; a[7] = (_Float16)f1.w;
        #pragma unroll
        for (int t = 0; t < 4; ++t) {
            half8 bf = *(const half8*)(wp + (size_t)(kc * 4 + t) * 512);
            acc[t] = mfma16(a, bf, acc[t]);
        }
    }
    pre_epi(acc, pre_b0, attL, asd, a_dst, xh, rowb, q, n);
}

// ---------------- single-launch CSR scan: decoupled lookback ------------------
// desc[b] = flag<<32 | value; flag 1 = block sum ready, 2 = inclusive ready.
// All 391 blocks co-resident (256 thr, low VGPR) -> lookback cannot stall.
__global__ __launch_bounds__(256) void k_scan(const unsigned long long* __restrict__ packed,
                                              int* __restrict__ row_ptr,
                                              float* __restrict__ asd,
                                              unsigned long long* __restrict__ desc) {
    __shared__ int tmp[256];
    __shared__ int exoff_sh;
    int tid = threadIdx.x, bid = blockIdx.x;
    int i = bid * 256 + tid;
    int v = 0;
    if (i < NN) {
        unsigned long long p = packed[i];
        v = (int)(p >> 48);
        // +1.0 = virtual self-loop weight; deg >= 1 always
        double deg = (double)(p & 0xFFFFFFFFFFFFULL) * (1.0 / 4294967296.0) + 1.0;
        asd[i * 4 + 2] = rsqrtf((float)deg);
    }
    tmp[tid] = v;
    __syncthreads();
    for (int off = 1; off < 256; off <<= 1) {
        int t = (tid >= off) ? tmp[tid - off] : 0;
        __syncthreads();
        tmp[tid] += t;
        __syncthreads();
    }
    int bsum = tmp[255];
    if (bid == 0) {
        if (tid == 0) {
            exoff_sh = 0;
            atomicExch(&desc[0], (2ULL << 32) | (unsigned long long)(unsigned)bsum);
            row_ptr[NN] = NE;
        }
    } else if (tid < 64) {
        if (tid == 0)
            atomicExch(&desc[bid], (1ULL << 32) | (unsigned long long)(unsigned)bsum);
        int sum = 0;
        int base = bid - 1;
        for (;;) {
            int j = base - tid;
            unsigned long long d = 0;
            bool have = (j >= 0);
            if (have) {
                do { d = atomicAdd((unsigned long long*)&desc[j], 0ULL); }
                while ((d >> 32) == 0ULL);
            }
            unsigned long long m2 = __ballot(have && ((d >> 32) == 2ULL));
            if (m2) {
                int stop = __ffsll((long long)m2) - 1;   // nearest inclusive entry
                if (tid <= stop) sum += (int)(d & 0xFFFFFFFFULL);
                break;
            }
            if (have) sum += (int)(d & 0xFFFFFFFFULL);
            base -= 64;
        }
        #pragma unroll
        for (int off = 32; off; off >>= 1) sum += __shfl_xor(sum, off);
        if (tid == 0) {
            exoff_sh = sum;
            atomicExch(&desc[bid],
                       (2ULL << 32) | (unsigned long long)(unsigned)(sum + bsum));
        }
    }
    __syncthreads();
    if (i < NN) row_ptr[i] = exoff_sh + tmp[tid] - v;
}

// ---------------- CSR fill: NO atomic, NO dinv gather -------------------------
__global__ __launch_bounds__(256) void k_fill(const int* __restrict__ src,
                                              const int* __restrict__ dst,
                                              const float* __restrict__ ew,
                                              const int* __restrict__ row_ptr,
                                              const int* __restrict__ ord,
                                              int2* __restrict__ recs) {
    int e = blockIdx.x * 256 + threadIdx.x;
    if (e >= NE) return;
    int d = dst[e];
    int pos = row_ptr[d] + ord[e];
    int2 r; r.x = src[e]; r.y = __float_as_int(ew[e]);
    recs[pos] = r;
}

// ---------------- fused GAT + SG aggregation in xh-space (64-wide) ------------
__global__ __launch_bounds__(256) void k_agg(const int* __restrict__ row_ptr,
                                             const int2* __restrict__ recs,
                                             const float* __restrict__ asd,
                                             const float* __restrict__ a_dst,
                                             const __half* __restrict__ xh,
                                             __half* __restrict__ agg) {
    __shared__ float4 einfo[4][64];
    int lane = threadIdx.x & 63;
    int wv = threadIdx.x >> 6;
    int d = blockIdx.x * 4 + wv;
    if (d >= NN) return;
    int p0 = row_ptr[d], p1 = row_ptr[d + 1];
    int nn = p1 - p0;                 // real edges; +1 virtual self-loop
    float2 ad2 = ((const float2*)a_dst)[d];
    const float4* asd4 = (const float4*)asd;
    int sub = lane >> 5;
    unsigned flb = (unsigned)(lane & 31) * 4u;   // byte offset of this lane's half2

    float g00 = 0.f, g01 = 0.f;   // head0 agg
    float g10 = 0.f, g11 = 0.f;   // head1 agg
    float s0a = 0.f, s1a = 0.f;   // sg agg

#define EDGE_ACC(E) do {                                                        \
        unsigned off_ = (unsigned)__float_as_int((E).w) + flb;                  \
        float2 v_ = __half22float2(*(const __half2*)((const char*)xh + off_));  \
        g00 = fmaf((E).x, v_.x, g00); g01 = fmaf((E).x, v_.y, g01);             \
        g10 = fmaf((E).y, v_.x, g10); g11 = fmaf((E).y, v_.y, g11);             \
        s0a = fmaf((E).z, v_.x, s0a); s1a = fmaf((E).z, v_.y, s1a);             \
    } while (0)

    if (nn <= 63) {
        // ---- fast path (max degree ~40 for this graph) ----
        int tot = nn + 1;
        float v0 = -INFINITY, v1 = -INFINITY, ewq = 0.f; int es = 0;
        if (lane < tot) {
            float wraw;
            if (lane < nn) {
                int2 rec = recs[p0 + lane];
                es = rec.x;
                wraw = __int_as_float(rec.y);
            } else { es = d; wraw = 1.f; }       // virtual self-loop
            float4 a4 = asd4[es];
            v0 = a4.x + ad2.x; v0 = (v0 > 0.f) ? v0 : 0.2f * v0;
            v1 = a4.y + ad2.y; v1 = (v1 > 0.f) ? v1 : 0.2f * v1;
            ewq = wraw * a4.z;                   // w * dinv[src]
        }
        float m0 = v0, m1 = v1;
        #pragma unroll
        for (int off = 32; off; off >>= 1) {
            m0 = fmaxf(m0, __shfl_xor(m0, off));
            m1 = fmaxf(m1, __shfl_xor(m1, off));
        }
        float e0 = (lane < tot) ? __expf(v0 - m0) : 0.f;
        float e1 = (lane < tot) ? __expf(v1 - m1) : 0.f;
        float s0 = e0, s1 = e1;
        #pragma unroll
        for (int off = 32; off; off >>= 1) {
            s0 += __shfl_xor(s0, off);
            s1 += __shfl_xor(s1, off);
        }
        if (lane < tot)
            einfo[wv][lane] = make_float4(e0 / (s0 + 1e-16f), e1 / (s1 + 1e-16f),
                                          ewq, __int_as_float(es << 7));
        // intra-wave LDS: DS pipe is in-order per wave, no barrier needed
        const float4* ep = &einfo[wv][sub];
        int j = 0;
        for (; j + 4 <= tot; j += 4) {
            float4 eA = ep[j];
            float4 eB = ep[j + 2];
            EDGE_ACC(eA);
            EDGE_ACC(eB);
        }
        for (; j + 2 <= tot; j += 2) {
            float4 eA = ep[j];
            EDGE_ACC(eA);
        }
        if (tot & 1) {
            if (sub == 0) {
                float4 eT = einfo[wv][tot - 1];
                EDGE_ACC(eT);
            }
        }
    } else {
        // ---- generic 3-pass path (degree > 63; dead for this graph) ----
        float4 aself = asd4[d];
        float sv0 = aself.x + ad2.x; sv0 = (sv0 > 0.f) ? sv0 : 0.2f * sv0;
        float sv1 = aself.y + ad2.y; sv1 = (sv1 > 0.f) ? sv1 : 0.2f * sv1;
        float m0 = sv0, m1 = sv1;
        for (int e = p0 + lane; e < p1; e += 64) {
            int s = recs[e].x;
            float4 a4 = asd4[s];
            float v0 = a4.x + ad2.x; v0 = (v0 > 0.f) ? v0 : 0.2f * v0;
            float v1 = a4.y + ad2.y; v1 = (v1 > 0.f) ? v1 : 0.2f * v1;
            m0 = fmaxf(m0, v0); m1 = fmaxf(m1, v1);
        }
        #pragma unroll
        for (int off = 32; off; off >>= 1) {
            m0 = fmaxf(m0, __shfl_xor(m0, off));
            m1 = fmaxf(m1, __shfl_xor(m1, off));
        }
        float s0 = 0.f, s1 = 0.f;
        for (int e = p0 + lane; e < p1; e += 64) {
            int s = recs[e].x;
            float4 a4 = asd4[s];
            float v0 = a4.x + ad2.x; v0 = (v0 > 0.f) ? v0 : 0.2f * v0;
            float v1 = a4.y + ad2.y; v1 = (v1 > 0.f) ? v1 : 0.2f * v1;
            s0 += __expf(v0 - m0); s1 += __expf(v1 - m1);
        }
        #pragma unroll
        for (int off = 32; off; off >>= 1) {
            s0 += __shfl_xor(s0, off);
            s1 += __shfl_xor(s1, off);
        }
        s0 += __expf(sv0 - m0); s1 += __expf(sv1 - m1);   // self contribution
        float inv0 = 1.f / (s0 + 1e-16f), inv1 = 1.f / (s1 + 1e-16f);
        for (int base = p0; base < p1; base += 64) {
            int e = base + lane;
            int nc = min(64, p1 - base);
            if (e < p1) {
                int2 rec = recs[e];
                int es = rec.x;
                float4 a4 = asd4[es];
                float v0 = a4.x + ad2.x; v0 = (v0 > 0.f) ? v0 : 0.2f * v0;
                float v1 = a4.y + ad2.y; v1 = (v1 > 0.f) ? v1 : 0.2f * v1;
                einfo[wv][lane] = make_float4(__expf(v0 - m0) * inv0,
                                              __expf(v1 - m1) * inv1,
                                              __int_as_float(rec.y) * a4.z,
                                              __int_as_float(es << 7));
            }
            const float4* ep = &einfo[wv][sub];
            int j = 0;
            for (; j + 2 <= nc; j += 2) {
                float4 eA = ep[j];
                EDGE_ACC(eA);
            }
            if (nc & 1) {
                if (sub == 0) {
                    float4 eT = einfo[wv][nc - 1];
                    EDGE_ACC(eT);
                }
            }
        }
        if (sub == 0) {   // virtual self-loop
            float4 eS = make_float4(__expf(sv0 - m0) * inv0,
                                    __expf(sv1 - m1) * inv1,
                                    aself.z, __int_as_float(d << 7));
            EDGE_ACC(eS);
        }
    }
#undef EDGE_ACC

    // combine the two half-wave partial sums
    g00 += __shfl_xor(g00, 32); g01 += __shfl_xor(g01, 32);
    g10 += __shfl_xor(g10, 32); g11 += __shfl_xor(g11, 32);
    s0a += __shfl_xor(s0a, 32); s1a += __shfl_xor(s1a, 32);

    float did = asd[d * 4 + 2];
    __half* op = agg + (size_t)d * 192;
    int fp = (lane & 31) * 2;
    if (lane < 32) {
        *(__half2*)(op + fp)       = __floats2half2_rn(g00, g01);
        *(__half2*)(op + 128 + fp) = __floats2half2_rn(s0a * did, s1a * did);
    } else {
        *(__half2*)(op + 64 + fp)  = __floats2half2_rn(g10, g11);
    }
}

// ---------------- fused post(l0) + pre(l1): agg -> LDS tile -> xh, att dots ---
// xA intermediate never touches HBM.
__global__ __launch_bounds__(256) void k_postpre(const __half* __restrict__ A,
                                                 const __half* __restrict__ Wfpq,
                                                 const float* __restrict__ gat_b,
                                                 const float* __restrict__ sg_b,
                                                 const __half* __restrict__ Wfpre,
                                                 const float* __restrict__ pre_b,
                                                 const float* __restrict__ attf,
                                                 float* __restrict__ asd,
                                                 float* __restrict__ a_dst,
                                                 __half* __restrict__ xh) {
    __shared__ __half tile[64][200];   // pad 192->200 halves: break bank aliasing
    int lane = threadIdx.x & 63, wv = threadIdx.x >> 6;
    int q = lane >> 4, n = lane & 15;
    int rowb = blockIdx.x * 64 + wv * 16;
    int rowA = rowb + n; if (rowA > NN - 1) rowA = NN - 1;
    {
        floatx4 acc[12] = {};
        const __half* ap = A + (size_t)rowA * 192 + q * 8;
        const __half* wp = Wfpq + q * 128 + n * 8;
        #pragma unroll
        for (int g = 0; g < 3; ++g) {
            #pragma unroll
            for (int kc = 0; kc < 2; ++kc) {
                half8 a = *(const half8*)(ap + g * 64 + kc * 32);
                #pragma unroll
                for (int tt = 0; tt < 4; ++tt) {
                    int t = g * 4 + tt;
                    half8 bf = *(const half8*)(wp + (size_t)(kc * 12 + t) * 512);
                    acc[t] = mfma16(a, bf, acc[t]);
                }
            }
        }
        #pragma unroll
        for (int t = 0; t < 12; ++t) {
            float bb = (t < 8) ? gat_b[t * 16 + n] : sg_b[(t - 8) * 16 + n];
            #pragma unroll
            for (int r = 0; r < 4; ++r) {
                int row = rowb + q * 4 + r;
                float v = fmaxf(acc[t][r] + bb, 0.f);
                tile[wv * 16 + q * 4 + r][t * 16 + n] =
                    (row < NN) ? __float2half(v) : __half(0.f);
            }
        }
    }
    __syncthreads();
    {
        floatx4 acc[4] = {};
        const __half* ap2 = &tile[wv * 16 + n][q * 8];
        const __half* wp = Wfpre + q * 128 + n * 8;
        #pragma unroll
        for (int kc = 0; kc < 6; ++kc) {
            half8 a = *(const half8*)(ap2 + kc * 32);
            #pragma unroll
            for (int t = 0; t < 4; ++t) {
                half8 bf = *(const half8*)(wp + (size_t)(kc * 4 + t) * 512);
                acc[t] = mfma16(a, bf, acc[t]);
            }
        }
        pre_epi(acc, pre_b, attf, asd, a_dst, xh, rowb, q, n);
    }
}

// ---------------- fused post(l1) + classifier + log_softmax -------------------
// xB intermediate never touches HBM.
__global__ __launch_bounds__(256) void k_postcls(const __half* __restrict__ A,
                                                 const __half* __restrict__ Wfpq,
                                                 const float* __restrict__ gat_b,
                                                 const float* __restrict__ sg_b,
                                                 const __half* __restrict__ Wfcls,
                                                 const float* __restrict__ b,
                                                 float* __restrict__ out) {
    __shared__ __half tile[64][200];
    int lane = threadIdx.x & 63, wv = threadIdx.x >> 6;
    int q = lane >> 4, n = lane & 15;
    int rowb = blockIdx.x * 64 + wv * 16;
    int rowA = rowb + n; if (rowA > NN - 1) rowA = NN - 1;
    {
        floatx4 acc[12] = {};
        const __half* ap = A + (size_t)rowA * 192 + q * 8;
        const __half* wp = Wfpq + q * 128 + n * 8;
        #pragma unroll
        for (int g = 0; g < 3; ++g) {
            #pragma unroll
            for (int kc = 0; kc < 2; ++kc) {
                half8 a = *(const half8*)(ap + g * 64 + kc * 32);
                #pragma unroll
                for (int tt = 0; tt < 4; ++tt) {
                    int t = g * 4 + tt;
                    half8 bf = *(const half8*)(wp + (size_t)(kc * 12 + t) * 512);
                    acc[t] = mfma16(a, bf, acc[t]);
                }
            }
        }
        #pragma unroll
        for (int t = 0; t < 12; ++t) {
            float bb = (t < 8) ? gat_b[t * 16 + n] : sg_b[(t - 8) * 16 + n];
            #pragma unroll
            for (int r = 0; r < 4; ++r) {
                int row = rowb + q * 4 + r;
                float v = fmaxf(acc[t][r] + bb, 0.f);
                tile[wv * 16 + q * 4 + r][t * 16 + n] =
                    (row < NN) ? __float2half(v) : __half(0.f);
            }
        }
    }
    __syncthreads();
    {
        floatx4 acc[2] = {};
        const __half* ap2 = &tile[wv * 16 + n][q * 8];
        const __half* wp = Wfcls + q * 128 + n * 8;
        #pragma unroll
        for (int kc = 0; kc < 6; ++kc) {
            half8 a = *(const half8*)(ap2 + kc * 32);
            #pragma unroll
            for (int t = 0; t < 2; ++t) {
                half8 bf = *(const half8*)(wp + (size_t)(kc * 2 + t) * 512);
                acc[t] = mfma16(a, bf, acc[t]);
            }
        }
        float b0 = b[n], b1 = b[16 + n];
        #pragma unroll
        for (int r = 0; r < 4; ++r) {
            float v0 = acc[0][r] + b0, v1 = acc[1][r] + b1;
            float mx = fmaxf(v0, v1);
            #pragma unroll
            for (int off = 1; off < 16; off <<= 1) mx = fmaxf(mx, __shfl_xor(mx, off));
            float sm = __expf(v0 - mx) + __expf(v1 - mx);
            #pragma unroll
            for (int off = 1; off < 16; off <<= 1) sm += __shfl_xor(sm, off);
            float lg = mx + __logf(sm);
            int row = rowb + q * 4 + r;
            if (row < NN) {
                out[(size_t)row * 32 + n]      = v0 - lg;
                out[(size_t)row * 32 + 16 + n] = v1 - lg;
            }
        }
    }
}

// ------------------------------------------------------------------------------
extern "C" void kernel_launch(void* const* d_in, const int* in_sizes, int n_in,
                              void* d_out, int out_size, void* d_ws, size_t ws_size,
                              hipStream_t stream) {
    const float* x   = (const float*)d_in[0];
    const int*   ei  = (const int*)d_in[1];
    const float* ew  = (const float*)d_in[2];
    const int* src = ei;
    const int* dst = ei + NE;

    const float* P[2][8];
    for (int l = 0; l < 2; ++l)
        for (int j = 0; j < 8; ++j)
            P[l][j] = (const float*)d_in[3 + l * 8 + j];
    const float* cls_W = (const float*)d_in[19];
    const float* cls_b = (const float*)d_in[20];

    float* ws = (float*)d_ws;
    const size_t n = NN;
    __half* xh_h = (__half*)(ws);             // [NN][64]  halves = 32N fl
    __half* agg  = (__half*)(ws + 32 * n);    // [NN][192] halves = 96N fl
    float* asd   = ws + 128 * n;              // [NN]{as0,as1,dinv,pad} = 4N fl
    float* a_dst = ws + 132 * n;              // 2N
    __half* Wf   = (__half*)(ws + 134 * n);   // 59392 halves = 29696 fl
    float* attf  = ws + 134 * n + 29696;      // 512 fl (folded att vectors)
    float* base2 = ws + 134 * n + 30208;      // byte offset div by 8 -> u64 ok
    unsigned long long* packed = (unsigned long long*)base2;  // NN u64
    unsigned long long* desc   = packed + NN;            // NBLK u64 (lookback)
    int*   row_ptr    = (int*)(desc + NBLK);             // NN+2 (pad for align)
    int*   ord        = row_ptr + (NN + 2);              // NE
    int2*  recs       = (int2*)(ord + NE);               // NE (8B-aligned)

    __half* Wf_pre1 = Wf + 16384;
    __half* Wf_pq0  = Wf + 28672;
    __half* Wf_pq1  = Wf + 40960;
    __half* Wf_cls  = Wf + 53248;

    const int TB = 256;
    int gb_edge  = (NE + TB - 1) / TB;     // == HB
    int gb_wave4 = (NN + 3) / 4;

    // ---- prep: histogram+ordinal | W swizzles+attf | pre32 GEMM (one dispatch)
    hipMemsetAsync(packed, 0, (NN + NBLK) * sizeof(unsigned long long), stream);
    k_prep<<<HB + WB + GB64, TB, 0, stream>>>(
        dst, ew, packed, ord, x,
        P[0][0], P[1][0], P[0][2], P[0][6], P[1][2], P[1][6], cls_W,
        P[0][3], P[0][4], P[1][3], P[1][4], P[0][1],
        Wf, attf, asd, a_dst, xh_h);

    // ---- single-launch decoupled-lookback scan ----
    k_scan<<<NBLK, TB, 0, stream>>>(packed, row_ptr, asd, desc);
    k_fill<<<gb_edge, TB, 0, stream>>>(src, dst, ew, row_ptr, ord, recs);

    // ---- layer 0 ----
    k_agg    <<<gb_wave4, TB, 0, stream>>>(row_ptr, recs, asd, a_dst, xh_h, agg);
    k_postpre<<<GB64, TB, 0, stream>>>(agg, Wf_pq0, P[0][5], P[0][7],
                                       Wf_pre1, P[1][1], attf + 256,
                                       asd, a_dst, xh_h);
    // ---- layer 1 ----
    k_agg    <<<gb_wave4, TB, 0, stream>>>(row_ptr, recs, asd, a_dst, xh_h, agg);
    k_postcls<<<GB64, TB, 0, stream>>>(agg, Wf_pq1, P[1][5], P[1][7],
                                       Wf_cls, cls_b, (float*)d_out);
}

// Round 4
// 464.315 us; speedup vs baseline: 1.2149x; 1.0396x over previous
//
#include <hip/hip_runtime.h>
#include <hip/hip_fp16.h>
#include <math.h>

#define NN 100000
#define NE 1200000
#define FIN 256
#define NBLK 391        // (NN + 255) / 256
#define HB 4688         // (NE + 255) / 256  -- histdeg blocks in k_prep
#define WB 234          // 59904 / 256 -- W-swizzle + attf blocks
#define GB64 1563       // (NN + 63) / 64  -- 64-row GEMM blocks

using half8   = __attribute__((ext_vector_type(8))) _Float16;
using floatx4 = __attribute__((ext_vector_type(4))) float;

__device__ __forceinline__ floatx4 mfma16(half8 a, half8 b, floatx4 c) {
    return __builtin_amdgcn_mfma_f32_16x16x32_f16(a, b, c, 0, 0, 0);
}

// ---------------- prep: histogram/ordinal + W swizzle + folded att ------------
// ZERO LDS: histogram blocks keep full occupancy (atomic-latency-bound).
// packed[d]: bits[48:63] = count, bits[0:47] = sum(w) in 2^-32 fixed point.
__global__ __launch_bounds__(256) void k_prep(const int* __restrict__ dst,
                                              const float* __restrict__ ew,
                                              unsigned long long* __restrict__ packed,
                                              int* __restrict__ ord,
                                              const float* __restrict__ W0,
                                              const float* __restrict__ W1,
                                              const float* __restrict__ Wg0,
                                              const float* __restrict__ Ws0,
                                              const float* __restrict__ Wg1,
                                              const float* __restrict__ Ws1,
                                              const float* __restrict__ Wc,
                                              const float* __restrict__ As0,
                                              const float* __restrict__ Ad0,
                                              const float* __restrict__ As1,
                                              const float* __restrict__ Ad1,
                                              __half* __restrict__ Wf,
                                              float* __restrict__ attf) {
    int bid = blockIdx.x;
    int tid = threadIdx.x;
    if (bid < HB) {
        // ---- edge histogram + ordinal capture ----
        int e = bid * 256 + tid;
        if (e >= NE) return;
        int d = dst[e]; float w = ew[e];
        unsigned long long add = (1ULL << 48)
            + (unsigned long long)((double)w * 4294967296.0);
        unsigned long long old = atomicAdd(&packed[d], add);
        ord[e] = (int)(old >> 48);
        return;
    }
    // ---- W swizzle (pre0, pre1, pq0, pq1, cls) + folded att vectors ----
    int o = (bid - HB) * 256 + tid;
    if (o >= 59904) return;
    if (o >= 59392) {
        // attf_v[c] = sum_j gat_W[c, h*64+j] * att[h, j]
        int idx = o - 59392;          // 0..511
        int layer = idx >> 8, rem = idx & 255;
        int v = rem >> 6, c = rem & 63, h = v & 1;
        const float* Wg = layer ? Wg1 : Wg0;
        const float* av = (v < 2) ? (layer ? As1 : As0) : (layer ? Ad1 : Ad0);
        float s = 0.f;
        for (int jj = 0; jj < 64; ++jj)
            s = fmaf(Wg[c * 128 + h * 64 + jj], av[h * 64 + jj], s);
        attf[idx] = s;
        return;
    }
    int lo, NT, N; const float* Wg; const float* Wsg = nullptr;
    if (o < 16384)      { lo = o;         NT = 4;  N = 64; Wg = W0; }
    else if (o < 28672) { lo = o - 16384; NT = 4;  N = 64; Wg = W1; }
    else if (o < 40960) { lo = o - 28672; NT = 12; N = 0;  Wg = Wg0; Wsg = Ws0; }
    else if (o < 53248) { lo = o - 40960; NT = 12; N = 0;  Wg = Wg1; Wsg = Ws1; }
    else                { lo = o - 53248; NT = 2;  N = 32; Wg = Wc; }
    int j = lo & 7, n = (lo >> 3) & 15, q = (lo >> 7) & 3, rest = lo >> 9;
    int t = rest % NT, kc = rest / NT;
    int k = kc * 32 + q * 8 + j, col = t * 16 + n;
    float v;
    if (Wsg) v = (col < 128) ? Wg[(size_t)k * 128 + col] : Wsg[(size_t)k * 64 + (col - 128)];
    else     v = Wg[(size_t)k * N + col];
    Wf[o] = __float2half(v);
}

// ---------------- shared epilogue for pre-linear: store xh + att dots ---------
// asd row = {a_src0, a_src1, dinv, pad} (dinv written by k_scan, untouched here)
__device__ __forceinline__ void pre_epi(floatx4* acc, const float* b, const float* attf,
                                        float* asd, float* a_dst, __half* out,
                                        int rowb, int q, int n) {
    float vs0[4] = {0,0,0,0}, vs1[4] = {0,0,0,0};
    float vd0[4] = {0,0,0,0}, vd1[4] = {0,0,0,0};
    #pragma unroll
    for (int t = 0; t < 4; ++t) {
        float bb  = b[t * 16 + n];
        float ws0 = attf[t * 16 + n],       ws1 = attf[64 + t * 16 + n];
        float wd0 = attf[128 + t * 16 + n], wd1 = attf[192 + t * 16 + n];
        #pragma unroll
        for (int r = 0; r < 4; ++r) {
            float xv = acc[t][r] + bb;
            int row = rowb + q * 4 + r;
            if (row < NN) out[(size_t)row * 64 + t * 16 + n] = __float2half(xv);
            vs0[r] = fmaf(xv, ws0, vs0[r]);
            vs1[r] = fmaf(xv, ws1, vs1[r]);
            vd0[r] = fmaf(xv, wd0, vd0[r]);
            vd1[r] = fmaf(xv, wd1, vd1[r]);
        }
    }
    #pragma unroll
    for (int off = 1; off < 16; off <<= 1) {
        #pragma unroll
        for (int r = 0; r < 4; ++r) {
            vs0[r] += __shfl_xor(vs0[r], off);
            vs1[r] += __shfl_xor(vs1[r], off);
            vd0[r] += __shfl_xor(vd0[r], off);
            vd1[r] += __shfl_xor(vd1[r], off);
        }
    }
    if (n == 0) {
        #pragma unroll
        for (int r = 0; r < 4; ++r) {
            int row = rowb + q * 4 + r;
            if (row < NN) {
                *(float2*)&asd[row * 4] = make_float2(vs0[r], vs1[r]);
                *(float2*)&a_dst[row * 2] = make_float2(vd0[r], vd1[r]);
            }
        }
    }
}

// ---------------- pre-linear (fp32 A): xh = x @ W[K,64] + b -> fp16 + att dots
template<int KK>
__global__ __launch_bounds__(256) void k_pre32(const float* __restrict__ A,
                                               const __half* __restrict__ Wf,
                                               const float* __restrict__ b,
                                               const float* __restrict__ attf,
                                               float* __restrict__ asd,
                                               float* __restrict__ a_dst,
                                               __half* __restrict__ out) {
    int lane = threadIdx.x & 63, wv = threadIdx.x >> 6;
    int q = lane >> 4, n = lane & 15;
    int rowb = blockIdx.x * 64 + wv * 16;
    int rowA = rowb + n; if (rowA > NN - 1) rowA = NN - 1;
    floatx4 acc[4] = {};
    const float* ap = A + (size_t)rowA * KK + q * 8;
    const __half* wp = Wf + q * 128 + n * 8;
    #pragma unroll
    for (int kc = 0; kc < KK / 32; ++kc) {
        float4 f0 = *(const float4*)(ap + kc * 32);
        float4 f1 = *(const float4*)(ap + kc * 32 + 4);
        half8 a;
        a[0] = (_Float16)f0.x; a[1] = (_Float16)f0.y;
        a[2] = (_Float16)f0.z; a[3] = (_Float16)f0.w;
        a[4] = (_Float16)f1.x; a[5] = (_Float16)f1.y;
        a[6] = (_Float16)f1.z; a[7] = (_Float16)f1.w;
        #pragma unroll
        for (int t = 0; t < 4; ++t) {
            half8 bf = *(const half8*)(wp + (size_t)(kc * 4 + t) * 512);
            acc[t] = mfma16(a, bf, acc[t]);
        }
    }
    pre_epi(acc, b, attf, asd, a_dst, out, rowb, q, n);
}

// ---------------- single-launch CSR scan: decoupled lookback ------------------
// desc[b] = flag<<32 | value; flag 1 = block sum ready, 2 = inclusive ready.
// All 391 blocks co-resident (256 thr, low VGPR) -> lookback cannot stall.
__global__ __launch_bounds__(256) void k_scan(const unsigned long long* __restrict__ packed,
                                              int* __restrict__ row_ptr,
                                              float* __restrict__ asd,
                                              unsigned long long* __restrict__ desc) {
    __shared__ int tmp[256];
    __shared__ int exoff_sh;
    int tid = threadIdx.x, bid = blockIdx.x;
    int i = bid * 256 + tid;
    int v = 0;
    if (i < NN) {
        unsigned long long p = packed[i];
        v = (int)(p >> 48);
        // +1.0 = virtual self-loop weight; deg >= 1 always
        double deg = (double)(p & 0xFFFFFFFFFFFFULL) * (1.0 / 4294967296.0) + 1.0;
        asd[i * 4 + 2] = rsqrtf((float)deg);
    }
    tmp[tid] = v;
    __syncthreads();
    for (int off = 1; off < 256; off <<= 1) {
        int t = (tid >= off) ? tmp[tid - off] : 0;
        __syncthreads();
        tmp[tid] += t;
        __syncthreads();
    }
    int bsum = tmp[255];
    if (bid == 0) {
        if (tid == 0) {
            exoff_sh = 0;
            atomicExch(&desc[0], (2ULL << 32) | (unsigned long long)(unsigned)bsum);
            row_ptr[NN] = NE;
        }
    } else if (tid < 64) {
        if (tid == 0)
            atomicExch(&desc[bid], (1ULL << 32) | (unsigned long long)(unsigned)bsum);
        int sum = 0;
        int base = bid - 1;
        for (;;) {
            int j = base - tid;
            unsigned long long d = 0;
            bool have = (j >= 0);
            if (have) {
                do { d = atomicAdd((unsigned long long*)&desc[j], 0ULL); }
                while ((d >> 32) == 0ULL);
            }
            unsigned long long m2 = __ballot(have && ((d >> 32) == 2ULL));
            if (m2) {
                int stop = __ffsll((long long)m2) - 1;   // nearest inclusive entry
                if (tid <= stop) sum += (int)(d & 0xFFFFFFFFULL);
                break;
            }
            if (have) sum += (int)(d & 0xFFFFFFFFULL);
            base -= 64;
        }
        #pragma unroll
        for (int off = 32; off; off >>= 1) sum += __shfl_xor(sum, off);
        if (tid == 0) {
            exoff_sh = sum;
            atomicExch(&desc[bid],
                       (2ULL << 32) | (unsigned long long)(unsigned)(sum + bsum));
        }
    }
    __syncthreads();
    if (i < NN) row_ptr[i] = exoff_sh + tmp[tid] - v;
}

// ---------------- CSR fill: NO atomic, NO dinv gather -------------------------
__global__ __launch_bounds__(256) void k_fill(const int* __restrict__ src,
                                              const int* __restrict__ dst,
                                              const float* __restrict__ ew,
                                              const int* __restrict__ row_ptr,
                                              const int* __restrict__ ord,
                                              int2* __restrict__ recs) {
    int e = blockIdx.x * 256 + threadIdx.x;
    if (e >= NE) return;
    int d = dst[e];
    int pos = row_ptr[d] + ord[e];
    int2 r; r.x = src[e]; r.y = __float_as_int(ew[e]);
    recs[pos] = r;
}

// ---------------- fused GAT + SG aggregation in xh-space (64-wide) ------------
__global__ __launch_bounds__(256) void k_agg(const int* __restrict__ row_ptr,
                                             const int2* __restrict__ recs,
                                             const float* __restrict__ asd,
                                             const float* __restrict__ a_dst,
                                             const __half* __restrict__ xh,
                                             __half* __restrict__ agg) {
    __shared__ float4 einfo[4][64];
    int lane = threadIdx.x & 63;
    int wv = threadIdx.x >> 6;
    int d = blockIdx.x * 4 + wv;
    if (d >= NN) return;
    int p0 = row_ptr[d], p1 = row_ptr[d + 1];
    int nn = p1 - p0;                 // real edges; +1 virtual self-loop
    float2 ad2 = ((const float2*)a_dst)[d];
    const float4* asd4 = (const float4*)asd;
    int sub = lane >> 5;
    unsigned flb = (unsigned)(lane & 31) * 4u;   // byte offset of this lane's half2

    float g00 = 0.f, g01 = 0.f;   // head0 agg
    float g10 = 0.f, g11 = 0.f;   // head1 agg
    float s0a = 0.f, s1a = 0.f;   // sg agg

#define EDGE_ACC(E) do {                                                        \
        unsigned off_ = (unsigned)__float_as_int((E).w) + flb;                  \
        float2 v_ = __half22float2(*(const __half2*)((const char*)xh + off_));  \
        g00 = fmaf((E).x, v_.x, g00); g01 = fmaf((E).x, v_.y, g01);             \
        g10 = fmaf((E).y, v_.x, g10); g11 = fmaf((E).y, v_.y, g11);             \
        s0a = fmaf((E).z, v_.x, s0a); s1a = fmaf((E).z, v_.y, s1a);             \
    } while (0)

    if (nn <= 63) {
        // ---- fast path (max degree ~40 for this graph) ----
        int tot = nn + 1;
        float v0 = -INFINITY, v1 = -INFINITY, ewq = 0.f; int es = 0;
        if (lane < tot) {
            float wraw;
            if (lane < nn) {
                int2 rec = recs[p0 + lane];
                es = rec.x;
                wraw = __int_as_float(rec.y);
            } else { es = d; wraw = 1.f; }       // virtual self-loop
            float4 a4 = asd4[es];
            v0 = a4.x + ad2.x; v0 = (v0 > 0.f) ? v0 : 0.2f * v0;
            v1 = a4.y + ad2.y; v1 = (v1 > 0.f) ? v1 : 0.2f * v1;
            ewq = wraw * a4.z;                   // w * dinv[src]
        }
        float m0 = v0, m1 = v1;
        #pragma unroll
        for (int off = 32; off; off >>= 1) {
            m0 = fmaxf(m0, __shfl_xor(m0, off));
            m1 = fmaxf(m1, __shfl_xor(m1, off));
        }
        float e0 = (lane < tot) ? __expf(v0 - m0) : 0.f;
        float e1 = (lane < tot) ? __expf(v1 - m1) : 0.f;
        float s0 = e0, s1 = e1;
        #pragma unroll
        for (int off = 32; off; off >>= 1) {
            s0 += __shfl_xor(s0, off);
            s1 += __shfl_xor(s1, off);
        }
        if (lane < tot)
            einfo[wv][lane] = make_float4(e0 / (s0 + 1e-16f), e1 / (s1 + 1e-16f),
                                          ewq, __int_as_float(es << 7));
        // intra-wave LDS: DS pipe is in-order per wave, no barrier needed
        const float4* ep = &einfo[wv][sub];
        int j = 0;
        for (; j + 4 <= tot; j += 4) {
            float4 eA = ep[j];
            float4 eB = ep[j + 2];
            EDGE_ACC(eA);
            EDGE_ACC(eB);
        }
        for (; j + 2 <= tot; j += 2) {
            float4 eA = ep[j];
            EDGE_ACC(eA);
        }
        if (tot & 1) {
            if (sub == 0) {
                float4 eT = einfo[wv][tot - 1];
                EDGE_ACC(eT);
            }
        }
    } else {
        // ---- generic 3-pass path (degree > 63; dead for this graph) ----
        float4 aself = asd4[d];
        float sv0 = aself.x + ad2.x; sv0 = (sv0 > 0.f) ? sv0 : 0.2f * sv0;
        float sv1 = aself.y + ad2.y; sv1 = (sv1 > 0.f) ? sv1 : 0.2f * sv1;
        float m0 = sv0, m1 = sv1;
        for (int e = p0 + lane; e < p1; e += 64) {
            int s = recs[e].x;
            float4 a4 = asd4[s];
            float v0 = a4.x + ad2.x; v0 = (v0 > 0.f) ? v0 : 0.2f * v0;
            float v1 = a4.y + ad2.y; v1 = (v1 > 0.f) ? v1 : 0.2f * v1;
            m0 = fmaxf(m0, v0); m1 = fmaxf(m1, v1);
        }
        #pragma unroll
        for (int off = 32; off; off >>= 1) {
            m0 = fmaxf(m0, __shfl_xor(m0, off));
            m1 = fmaxf(m1, __shfl_xor(m1, off));
        }
        float s0 = 0.f, s1 = 0.f;
        for (int e = p0 + lane; e < p1; e += 64) {
            int s = recs[e].x;
            float4 a4 = asd4[s];
            float v0 = a4.x + ad2.x; v0 = (v0 > 0.f) ? v0 : 0.2f * v0;
            float v1 = a4.y + ad2.y; v1 = (v1 > 0.f) ? v1 : 0.2f * v1;
            s0 += __expf(v0 - m0); s1 += __expf(v1 - m1);
        }
        #pragma unroll
        for (int off = 32; off; off >>= 1) {
            s0 += __shfl_xor(s0, off);
            s1 += __shfl_xor(s1, off);
        }
        s0 += __expf(sv0 - m0); s1 += __expf(sv1 - m1);   // self contribution
        float inv0 = 1.f / (s0 + 1e-16f), inv1 = 1.f / (s1 + 1e-16f);
        for (int base = p0; base < p1; base += 64) {
            int e = base + lane;
            int nc = min(64, p1 - base);
            if (e < p1) {
                int2 rec = recs[e];
                int es = rec.x;
                float4 a4 = asd4[es];
                float v0 = a4.x + ad2.x; v0 = (v0 > 0.f) ? v0 : 0.2f * v0;
                float v1 = a4.y + ad2.y; v1 = (v1 > 0.f) ? v1 : 0.2f * v1;
                einfo[wv][lane] = make_float4(__expf(v0 - m0) * inv0,
                                              __expf(v1 - m1) * inv1,
                                              __int_as_float(rec.y) * a4.z,
                                              __int_as_float(es << 7));
            }
            const float4* ep = &einfo[wv][sub];
            int j = 0;
            for (; j + 2 <= nc; j += 2) {
                float4 eA = ep[j];
                EDGE_ACC(eA);
            }
            if (nc & 1) {
                if (sub == 0) {
                    float4 eT = einfo[wv][nc - 1];
                    EDGE_ACC(eT);
                }
            }
        }
        if (sub == 0) {   // virtual self-loop
            float4 eS = make_float4(__expf(sv0 - m0) * inv0,
                                    __expf(sv1 - m1) * inv1,
                                    aself.z, __int_as_float(d << 7));
            EDGE_ACC(eS);
        }
    }
#undef EDGE_ACC

    // combine the two half-wave partial sums
    g00 += __shfl_xor(g00, 32); g01 += __shfl_xor(g01, 32);
    g10 += __shfl_xor(g10, 32); g11 += __shfl_xor(g11, 32);
    s0a += __shfl_xor(s0a, 32); s1a += __shfl_xor(s1a, 32);

    float did = asd[d * 4 + 2];
    __half* op = agg + (size_t)d * 192;
    int fp = (lane & 31) * 2;
    if (lane < 32) {
        *(__half2*)(op + fp)       = __floats2half2_rn(g00, g01);
        *(__half2*)(op + 128 + fp) = __floats2half2_rn(s0a * did, s1a * did);
    } else {
        *(__half2*)(op + 64 + fp)  = __floats2half2_rn(g10, g11);
    }
}

// ---------------- fused post(l0) + pre(l1): agg -> LDS tile -> xh, att dots ---
// xA intermediate never touches HBM.
__global__ __launch_bounds__(256) void k_postpre(const __half* __restrict__ A,
                                                 const __half* __restrict__ Wfpq,
                                                 const float* __restrict__ gat_b,
                                                 const float* __restrict__ sg_b,
                                                 const __half* __restrict__ Wfpre,
                                                 const float* __restrict__ pre_b,
                                                 const float* __restrict__ attf,
                                                 float* __restrict__ asd,
                                                 float* __restrict__ a_dst,
                                                 __half* __restrict__ xh) {
    __shared__ __half tile[64][200];   // pad 192->200 halves: break bank aliasing
    int lane = threadIdx.x & 63, wv = threadIdx.x >> 6;
    int q = lane >> 4, n = lane & 15;
    int rowb = blockIdx.x * 64 + wv * 16;
    int rowA = rowb + n; if (rowA > NN - 1) rowA = NN - 1;
    {
        floatx4 acc[12] = {};
        const __half* ap = A + (size_t)rowA * 192 + q * 8;
        const __half* wp = Wfpq + q * 128 + n * 8;
        #pragma unroll
        for (int g = 0; g < 3; ++g) {
            #pragma unroll
            for (int kc = 0; kc < 2; ++kc) {
                half8 a = *(const half8*)(ap + g * 64 + kc * 32);
                #pragma unroll
                for (int tt = 0; tt < 4; ++tt) {
                    int t = g * 4 + tt;
                    half8 bf = *(const half8*)(wp + (size_t)(kc * 12 + t) * 512);
                    acc[t] = mfma16(a, bf, acc[t]);
                }
            }
        }
        #pragma unroll
        for (int t = 0; t < 12; ++t) {
            float bb = (t < 8) ? gat_b[t * 16 + n] : sg_b[(t - 8) * 16 + n];
            #pragma unroll
            for (int r = 0; r < 4; ++r) {
                int row = rowb + q * 4 + r;
                float v = fmaxf(acc[t][r] + bb, 0.f);
                tile[wv * 16 + q * 4 + r][t * 16 + n] =
                    (row < NN) ? __float2half(v) : __half(0.f);
            }
        }
    }
    __syncthreads();
    {
        floatx4 acc[4] = {};
        const __half* ap2 = &tile[wv * 16 + n][q * 8];
        const __half* wp = Wfpre + q * 128 + n * 8;
        #pragma unroll
        for (int kc = 0; kc < 6; ++kc) {
            half8 a = *(const half8*)(ap2 + kc * 32);
            #pragma unroll
            for (int t = 0; t < 4; ++t) {
                half8 bf = *(const half8*)(wp + (size_t)(kc * 4 + t) * 512);
                acc[t] = mfma16(a, bf, acc[t]);
            }
        }
        pre_epi(acc, pre_b, attf, asd, a_dst, xh, rowb, q, n);
    }
}

// ---------------- fused post(l1) + classifier + log_softmax -------------------
// xB intermediate never touches HBM.
__global__ __launch_bounds__(256) void k_postcls(const __half* __restrict__ A,
                                                 const __half* __restrict__ Wfpq,
                                                 const float* __restrict__ gat_b,
                                                 const float* __restrict__ sg_b,
                                                 const __half* __restrict__ Wfcls,
                                                 const float* __restrict__ b,
                                                 float* __restrict__ out) {
    __shared__ __half tile[64][200];
    int lane = threadIdx.x & 63, wv = threadIdx.x >> 6;
    int q = lane >> 4, n = lane & 15;
    int rowb = blockIdx.x * 64 + wv * 16;
    int rowA = rowb + n; if (rowA > NN - 1) rowA = NN - 1;
    {
        floatx4 acc[12] = {};
        const __half* ap = A + (size_t)rowA * 192 + q * 8;
        const __half* wp = Wfpq + q * 128 + n * 8;
        #pragma unroll
        for (int g = 0; g < 3; ++g) {
            #pragma unroll
            for (int kc = 0; kc < 2; ++kc) {
                half8 a = *(const half8*)(ap + g * 64 + kc * 32);
                #pragma unroll
                for (int tt = 0; tt < 4; ++tt) {
                    int t = g * 4 + tt;
                    half8 bf = *(const half8*)(wp + (size_t)(kc * 12 + t) * 512);
                    acc[t] = mfma16(a, bf, acc[t]);
                }
            }
        }
        #pragma unroll
        for (int t = 0; t < 12; ++t) {
            float bb = (t < 8) ? gat_b[t * 16 + n] : sg_b[(t - 8) * 16 + n];
            #pragma unroll
            for (int r = 0; r < 4; ++r) {
                int row = rowb + q * 4 + r;
                float v = fmaxf(acc[t][r] + bb, 0.f);
                tile[wv * 16 + q * 4 + r][t * 16 + n] =
                    (row < NN) ? __float2half(v) : __half(0.f);
            }
        }
    }
    __syncthreads();
    {
        floatx4 acc[2] = {};
        const __half* ap2 = &tile[wv * 16 + n][q * 8];
        const __half* wp = Wfcls + q * 128 + n * 8;
        #pragma unroll
        for (int kc = 0; kc < 6; ++kc) {
            half8 a = *(const half8*)(ap2 + kc * 32);
            #pragma unroll
            for (int t = 0; t < 2; ++t) {
                half8 bf = *(const half8*)(wp + (size_t)(kc * 2 + t) * 512);
                acc[t] = mfma16(a, bf, acc[t]);
            }
        }
        float b0 = b[n], b1 = b[16 + n];
        #pragma unroll
        for (int r = 0; r < 4; ++r) {
            float v0 = acc[0][r] + b0, v1 = acc[1][r] + b1;
            float mx = fmaxf(v0, v1);
            #pragma unroll
            for (int off = 1; off < 16; off <<= 1) mx = fmaxf(mx, __shfl_xor(mx, off));
            float sm = __expf(v0 - mx) + __expf(v1 - mx);
            #pragma unroll
            for (int off = 1; off < 16; off <<= 1) sm += __shfl_xor(sm, off);
            float lg = mx + __logf(sm);
            int row = rowb + q * 4 + r;
            if (row < NN) {
                out[(size_t)row * 32 + n]      = v0 - lg;
                out[(size_t)row * 32 + 16 + n] = v1 - lg;
            }
        }
    }
}

// ------------------------------------------------------------------------------
extern "C" void kernel_launch(void* const* d_in, const int* in_sizes, int n_in,
                              void* d_out, int out_size, void* d_ws, size_t ws_size,
                              hipStream_t stream) {
    const float* x   = (const float*)d_in[0];
    const int*   ei  = (const int*)d_in[1];
    const float* ew  = (const float*)d_in[2];
    const int* src = ei;
    const int* dst = ei + NE;

    const float* P[2][8];
    for (int l = 0; l < 2; ++l)
        for (int j = 0; j < 8; ++j)
            P[l][j] = (const float*)d_in[3 + l * 8 + j];
    const float* cls_W = (const float*)d_in[19];
    const float* cls_b = (const float*)d_in[20];

    float* ws = (float*)d_ws;
    const size_t n = NN;
    __half* xh_h = (__half*)(ws);             // [NN][64]  halves = 32N fl
    __half* agg  = (__half*)(ws + 32 * n);    // [NN][192] halves = 96N fl
    float* asd   = ws + 128 * n;              // [NN]{as0,as1,dinv,pad} = 4N fl
    float* a_dst = ws + 132 * n;              // 2N
    __half* Wf   = (__half*)(ws + 134 * n);   // 59392 halves = 29696 fl
    float* attf  = ws + 134 * n + 29696;      // 512 fl (folded att vectors)
    float* base2 = ws + 134 * n + 30208;      // byte offset div by 8 -> u64 ok
    unsigned long long* packed = (unsigned long long*)base2;  // NN u64
    unsigned long long* desc   = packed + NN;            // NBLK u64 (lookback)
    int*   row_ptr    = (int*)(desc + NBLK);             // NN+2 (pad for align)
    int*   ord        = row_ptr + (NN + 2);              // NE
    int2*  recs       = (int2*)(ord + NE);               // NE (8B-aligned)

    __half* Wf_pre0 = Wf;
    __half* Wf_pre1 = Wf + 16384;
    __half* Wf_pq0  = Wf + 28672;
    __half* Wf_pq1  = Wf + 40960;
    __half* Wf_cls  = Wf + 53248;

    const int TB = 256;
    int gb_edge  = (NE + TB - 1) / TB;     // == HB
    int gb_wave4 = (NN + 3) / 4;

    // ---- prep: histogram+ordinal + W swizzles + attf (zero LDS, one dispatch)
    hipMemsetAsync(packed, 0, (NN + NBLK) * sizeof(unsigned long long), stream);
    k_prep<<<HB + WB, TB, 0, stream>>>(
        dst, ew, packed, ord,
        P[0][0], P[1][0], P[0][2], P[0][6], P[1][2], P[1][6], cls_W,
        P[0][3], P[0][4], P[1][3], P[1][4],
        Wf, attf);

    // ---- pre32 GEMM (depends only on prep's W-swizzle portion) ----
    k_pre32<256><<<GB64, TB, 0, stream>>>(x, Wf_pre0, P[0][1],
                                          attf, asd, a_dst, xh_h);

    // ---- single-launch decoupled-lookback scan + fill ----
    k_scan<<<NBLK, TB, 0, stream>>>(packed, row_ptr, asd, desc);
    k_fill<<<gb_edge, TB, 0, stream>>>(src, dst, ew, row_ptr, ord, recs);

    // ---- layer 0 ----
    k_agg    <<<gb_wave4, TB, 0, stream>>>(row_ptr, recs, asd, a_dst, xh_h, agg);
    k_postpre<<<GB64, TB, 0, stream>>>(agg, Wf_pq0, P[0][5], P[0][7],
                                       Wf_pre1, P[1][1], attf + 256,
                                       asd, a_dst, xh_h);
    // ---- layer 1 ----
    k_agg    <<<gb_wave4, TB, 0, stream>>>(row_ptr, recs, asd, a_dst, xh_h, agg);
    k_postcls<<<GB64, TB, 0, stream>>>(agg, Wf_pq1, P[1][5], P[1][7],
                                       Wf_cls, cls_b, (float*)d_out);
}